// Round 4
// baseline (212.031 us; speedup 1.0000x reference)
//
#include <hip/hip_runtime.h>
#include <math.h>

// Problem constants (from reference)
#define NQ 32768   // query points (pos1)
#define MC 8192    // source points (pos2)
#define CC 128     // channels
#define EPS_BN 1e-5f
#define EPS_D  1e-8

#define DBL_BIG 1e300
#define IDX_BIG 0x7fffffff

// KNN config (R10: 4-deep SMEM pipeline; otherwise R9 structure)
#define QB  64          // queries per block (1 per lane)
#define TB  256         // threads per block (4 waves)
#define NW  4           // waves per block
#define PCE (MC / 4)    // piece of M per block = 2048
#define SLCW (PCE / NW) // per-wave candidate slice = 512
#define NG  (SLCW / 4)  // 4-candidate groups per wave = 128
#define KMASK 0xFFFFE000u   // keep sign+exp+10 mantissa bits
#define IMASK 0x1FFFu       // 13-bit index (M=8192)
#define NSURV 48            // survivors per query (4 pieces x 4 waves x 3)
#define KNN_B ((NQ / QB) * 4)   // 2048 scan blocks
#define GEMM_B (NQ / 64)        // 512 row-blocks
#define NGRP 8                  // stats atomic groups (2048 addresses)

typedef __attribute__((ext_vector_type(8))) short bf16x8;   // 8 bf16 (4 VGPRs)
typedef __attribute__((ext_vector_type(4))) float floatx4;  // MFMA accumulator
typedef unsigned short ushort_t;

// RNE fp32 -> bf16 pair packed in u32 (lo = a, hi = b)
__device__ __forceinline__ unsigned bf16pair(float a, float b) {
    unsigned ua = __float_as_uint(a); ua = (ua + 0x7FFFu + ((ua >> 16) & 1u)) >> 16;
    unsigned ub = __float_as_uint(b); ub = (ub + 0x7FFFu + ((ub >> 16) & 1u)) >> 16;
    return ua | (ub << 16);
}
__device__ __forceinline__ ushort_t bf16one(float a) {
    unsigned ua = __float_as_uint(a);
    return (ushort_t)((ua + 0x7FFFu + ((ua >> 16) & 1u)) >> 16);
}
// unpack u32 = (lo bf16, hi bf16) -> 2 fp32
__device__ __forceinline__ float bflo(unsigned u) { return __uint_as_float(u << 16); }
__device__ __forceinline__ float bfhi(unsigned u) { return __uint_as_float(u & 0xFFFF0000u); }

// Branchless insert of x into ascending top-3 (k0<=k1<=k2):
// 1x v_min_f32 + 2x v_med3_f32.
__device__ __forceinline__ void ins3(float& k0, float& k1, float& k2, float x) {
    const float n0 = fminf(k0, x);
    const float n1 = __builtin_amdgcn_fmed3f(k0, k1, x);
    const float n2 = __builtin_amdgcn_fmed3f(k1, k2, x);
    k0 = n0; k1 = n1; k2 = n2;
}

// Sortable float key from prepacked candidate c = {x, y, z, 0.5|c|^2}:
// t = 0.5*d^2 (+ ~1e-6 cancellation noise); low 13 mantissa bits replaced by
// the candidate index. Each VALU op reads at most 1 SGPR.
__device__ __forceinline__ float mkk(float nx, float ny, float nz, float hp,
                                     float4 c, unsigned j) {
    float t = c.w + hp;                 // v_add_f32 t, s_hc, v_hp
    t = fmaf(nz, c.z, t);               // v_fmac    t, s_cz, v_nz
    t = fmaf(ny, c.y, t);
    t = fmaf(nx, c.x, t);
    const unsigned u = (__float_as_uint(t) & KMASK) | (j & ~KMASK);
    return __uint_as_float(u);
}

// ---------------------------------------------------------------------------
// Pack pos2 -> {x, y, z, 0.5|c|^2} (16 B/cand, 128 KB, L2-resident) + 16-entry
// pad (4-deep prefetch overshoot guard). Must run before knn scan blocks.
// ---------------------------------------------------------------------------
__global__ __launch_bounds__(TB) void pack_kernel(const float* __restrict__ pos2,
                                                  float4* __restrict__ pos2pk) {
    const int c0 = blockIdx.x * (MC / 8);
#pragma unroll
    for (int c = c0 + threadIdx.x; c < c0 + MC / 8; c += TB) {
        const float x = pos2[c * 3 + 0];
        const float y = pos2[c * 3 + 1];
        const float z = pos2[c * 3 + 2];
        float4 v;
        v.x = x; v.y = y; v.z = z;
        v.w = 0.5f * fmaf(x, x, fmaf(y, y, z * z));
        pos2pk[c] = v;
    }
    if (blockIdx.x == 0 && threadIdx.x < 16) {
        float4 zf; zf.x = 0.f; zf.y = 0.f; zf.z = 0.f; zf.w = 0.f;
        pos2pk[MC + threadIdx.x] = zf;   // overshoot pad
    }
}

// ---------------------------------------------------------------------------
// KNN scan + piggy-backed weight conversion + stats zero.
// Blocks [0, KNN_B): 64 queries (1/lane) x one quarter of M; 4 waves each
//   scan a 512-cand slice streamed through SGPRs with a 4-deep software
//   pipeline (3-4 outstanding s_load_dwordx16 per wave to cover L2 latency).
//   No LDS, no barriers in the main loop. Top-3/slice via med3 sorted-insert.
// Blocks [KNN_B, KNN_B+16): convert W0/W1/W2 fp32 -> bf16; block KNN_B also
//   zeroes the 3 layers' stats accumulators.
// ---------------------------------------------------------------------------
__global__ __launch_bounds__(TB) void knn_kernel(const float* __restrict__ pos1,
                                                 const float4* __restrict__ pos2pk,
                                                 unsigned* __restrict__ skeys,
                                                 const float* __restrict__ W0,
                                                 const float* __restrict__ W1,
                                                 const float* __restrict__ W2,
                                                 ushort_t* __restrict__ Wbf,
                                                 float* __restrict__ stats) {
    __shared__ unsigned skl[QB][13];   // 3.3 KB survivor staging (13: conflict-free)

    if (blockIdx.x >= KNN_B) {                 // ---- prep blocks ----
        const int pb = blockIdx.x - KNN_B;     // 0..15
        const int f = pb * TB + threadIdx.x;   // float4 index within a layer
        const float* Ws[3] = {W0, W1, W2};
#pragma unroll
        for (int l = 0; l < 3; ++l) {
            const float4 v = ((const float4*)Ws[l])[f];
            unsigned* dst = (unsigned*)(Wbf + (size_t)l * CC * CC);
            dst[f * 2 + 0] = bf16pair(v.x, v.y);
            dst[f * 2 + 1] = bf16pair(v.z, v.w);
        }
        if (pb == 0)
            for (int i = threadIdx.x; i < 3 * NGRP * 256; i += TB) stats[i] = 0.f;
        return;
    }

    const int piece = blockIdx.x & 3;
    const int bq    = blockIdx.x >> 2;
    const int ln = threadIdx.x & 63;   // lane = query owner
    // force wave id uniform so the candidate address scalarizes to s_load
    const int wvu = __builtin_amdgcn_readfirstlane((int)(threadIdx.x >> 6));
    const int q  = bq * QB + ln;

    const float px = pos1[q * 3 + 0];
    const float py = pos1[q * 3 + 1];
    const float pz = pos1[q * 3 + 2];
    const float nx = -px, ny = -py, nz = -pz;
    const float hp = 0.5f * fmaf(px, px, fmaf(py, py, pz * pz));

    const int jb = piece * PCE + wvu * SLCW;
    const float4* cp = pos2pk + jb;

    const float KINIT = __uint_as_float(0x7F000000u);   // large finite sentinel
    float k0 = KINIT, k1 = KINIT, k2 = KINIT;

#define LOADG(v0, v1, v2, v3, g) { v0 = cp[(g)*4+0]; v1 = cp[(g)*4+1]; \
                                   v2 = cp[(g)*4+2]; v3 = cp[(g)*4+3]; }
#define CONSG(v0, v1, v2, v3, g) { const unsigned j0 = (unsigned)(jb + (g)*4); \
        ins3(k0, k1, k2, mkk(nx, ny, nz, hp, v0, j0 + 0)); \
        ins3(k0, k1, k2, mkk(nx, ny, nz, hp, v1, j0 + 1)); \
        ins3(k0, k1, k2, mkk(nx, ny, nz, hp, v2, j0 + 2)); \
        ins3(k0, k1, k2, mkk(nx, ny, nz, hp, v3, j0 + 3)); }

    float4 A0, A1, A2, A3, B0, B1, B2, B3, C0, C1, C2, C3, D0, D1, D2, D3;
    LOADG(A0, A1, A2, A3, 0);
    LOADG(B0, B1, B2, B3, 1);
    LOADG(C0, C1, C2, C3, 2);
    for (int g = 0; g < NG; g += 4) {
        LOADG(D0, D1, D2, D3, g + 3);   // keep 3-4 groups in flight
        CONSG(A0, A1, A2, A3, g);
        LOADG(A0, A1, A2, A3, g + 4);   // overshoots into pad on last iter
        CONSG(B0, B1, B2, B3, g + 1);
        LOADG(B0, B1, B2, B3, g + 5);
        CONSG(C0, C1, C2, C3, g + 2);
        LOADG(C0, C1, C2, C3, g + 6);
        CONSG(D0, D1, D2, D3, g + 3);
    }
#undef LOADG
#undef CONSG

    skl[ln][wvu * 3 + 0] = __float_as_uint(k0);
    skl[ln][wvu * 3 + 1] = __float_as_uint(k1);
    skl[ln][wvu * 3 + 2] = __float_as_uint(k2);
    __syncthreads();

    // coalesced dump: query q's survivors at skeys[q*48 + piece*12 + slot]
    {
        const int ql = threadIdx.x >> 2;
        const int sp = (threadIdx.x & 3) * 3;
        unsigned* dst = &skeys[(size_t)(bq * QB + ql) * NSURV + piece * 12 + sp];
        dst[0] = skl[ql][sp + 0];
        dst[1] = skl[ql][sp + 1];
        dst[2] = skl[ql][sp + 2];
    }
}

// ---------------------------------------------------------------------------
// bf16-MFMA fused layer GEMM: Y = Xin @ W^T + bias (fp32 accumulate).
//   MODE 0 (CSPLIT=1): prologue re-ranks this block's own 64 queries (fp64
//           exact) from skeys, then Xin = interp(feat2, idx, w). Y out: bf16.
//   MODE 1 (CSPLIT=2): output cols split across 2 blocks (halves LDS -> 4
//           blocks/CU for latency hiding); prologue reduces statsIn[8][256]
//           -> BN scale/shift, then Xin = relu(Xbf16 * sc + sh). Y out: bf16.
// Stats: per-column partials; group keyed by row-block -> 64 adds/address.
// grid = GEMM_B * CSPLIT, block = 256.
// ---------------------------------------------------------------------------
template <int MODE, int CSPLIT>
__global__ __launch_bounds__(256) void gemm_mfma(const void* __restrict__ Xsrc_,
                                                 const unsigned* __restrict__ skeys,
                                                 const float* __restrict__ pos1,
                                                 const float* __restrict__ pos2,
                                                 const float* __restrict__ statsIn,
                                                 const float* __restrict__ gIn,
                                                 const float* __restrict__ beIn,
                                                 const ushort_t* __restrict__ Wb,
                                                 const float* __restrict__ bias,
                                                 ushort_t* __restrict__ Y,
                                                 float* __restrict__ statsOut) {
    constexpr int NCT = 8 / CSPLIT;            // col tiles per block (8 or 4)
    __shared__ __align__(16) short xa[64][136];        // 64 rows x 128 k bf16
    __shared__ __align__(16) short wb[NCT * 16][136];  // out-cols x 128 k bf16
    __shared__ float blk_s[NCT * 16], blk_q[NCT * 16]; // epilogue stat accum
    __shared__ float sc_l[CC], sh_l[CC];               // MODE 1 BN scale/shift

    const int cb = blockIdx.x % CSPLIT;
    const int rb = blockIdx.x / CSPLIT;
    const int row0 = rb * 64;
    const int colbase = cb * NCT * 16;

    // ---- X tile staging (+ fused transform) ----
    if constexpr (MODE == 0) {
        const float* feat2 = (const float*)Xsrc_;
        __shared__ int   lidx[QB][3];
        __shared__ float lw[QB][3];
        {   // exact fp64 re-rank of this block's 64 queries; 4 thr/query
            double* rrd = (double*)&xa[0][0];   // [64][4][3] = 6144 B scratch
            int*    rri = (int*)&wb[0][0];      // [64][4][3] = 3072 B scratch
            const int ql = threadIdx.x >> 2;
            const int pp = threadIdx.x & 3;
            const int qg = row0 + ql;
            const double qx = (double)pos1[qg * 3 + 0];
            const double qy = (double)pos1[qg * 3 + 1];
            const double qz = (double)pos1[qg * 3 + 2];
            double b0 = DBL_BIG, b1 = DBL_BIG, b2 = DBL_BIG;
            int    j0 = IDX_BIG, j1 = IDX_BIG, j2 = IDX_BIG;
            const uint4* kp = (const uint4*)(skeys + (size_t)qg * NSURV + pp * 12);
#pragma unroll
            for (int gi = 0; gi < 3; ++gi) {
                const uint4 kk = kp[gi];
                const unsigned ks[4] = {kk.x, kk.y, kk.z, kk.w};
#pragma unroll
                for (int u = 0; u < 4; ++u) {
                    const int id = (int)(ks[u] & IMASK);
                    const double x = (double)pos2[id * 3 + 0];
                    const double y = (double)pos2[id * 3 + 1];
                    const double z = (double)pos2[id * 3 + 2];
                    const double ax = qx - x, ay = qy - y, az = qz - z;
                    const double d = ax * ax + ay * ay + az * az;
                    const bool l2 = (d < b2) || (d == b2 && id < j2);
                    if (l2) {
                        const bool l1 = (d < b1) || (d == b1 && id < j1);
                        const bool l0 = (d < b0) || (d == b0 && id < j0);
                        b2 = l1 ? b1 : d;              j2 = l1 ? j1 : id;
                        b1 = l1 ? (l0 ? b0 : d) : b1;  j1 = l1 ? (l0 ? j0 : id) : j1;
                        b0 = l0 ? d : b0;              j0 = l0 ? id : j0;
                    }
                }
            }
            const int base = (ql * 4 + pp) * 3;
            rrd[base + 0] = b0; rri[base + 0] = j0;
            rrd[base + 1] = b1; rri[base + 1] = j1;
            rrd[base + 2] = b2; rri[base + 2] = j2;
            __syncthreads();
            if (threadIdx.x < QB) {
                const int qq = threadIdx.x;
                double c0 = DBL_BIG, c1 = DBL_BIG, c2 = DBL_BIG;
                int    i0 = IDX_BIG, i1 = IDX_BIG, i2 = IDX_BIG;
#pragma unroll
                for (int s = 0; s < 12; ++s) {
                    const double d = rrd[qq * 12 + s];
                    const int   id = rri[qq * 12 + s];
                    const bool l2 = (d < c2) || (d == c2 && id < i2);
                    if (l2) {
                        const bool l1 = (d < c1) || (d == c1 && id < i1);
                        const bool l0 = (d < c0) || (d == c0 && id < i0);
                        c2 = l1 ? c1 : d;              i2 = l1 ? i1 : id;
                        c1 = l1 ? (l0 ? c0 : d) : c1;  i1 = l1 ? (l0 ? i0 : id) : i1;
                        c0 = l0 ? d : c0;              i0 = l0 ? id : i0;
                    }
                }
                const double r0 = 1.0 / (c0 + EPS_D);
                const double r1 = 1.0 / (c1 + EPS_D);
                const double r2 = 1.0 / (c2 + EPS_D);
                const double inv = 1.0 / (r0 + r1 + r2);
                lidx[qq][0] = i0; lidx[qq][1] = i1; lidx[qq][2] = i2;
                lw[qq][0] = (float)(r0 * inv);
                lw[qq][1] = (float)(r1 * inv);
                lw[qq][2] = (float)(r2 * inv);
            }
            __syncthreads();
        }
        if (threadIdx.x < NCT * 16) { blk_s[threadIdx.x] = 0.f; blk_q[threadIdx.x] = 0.f; }
#pragma unroll
        for (int e = threadIdx.x; e < 64 * 32; e += 256) {
            const int r = e >> 5, c4 = e & 31;
            const int i0 = lidx[r][0], i1 = lidx[r][1], i2 = lidx[r][2];
            const float w0 = lw[r][0], w1 = lw[r][1], w2 = lw[r][2];
            const float4 f0 = *(const float4*)&feat2[(size_t)i0 * CC + c4 * 4];
            const float4 f1 = *(const float4*)&feat2[(size_t)i1 * CC + c4 * 4];
            const float4 f2 = *(const float4*)&feat2[(size_t)i2 * CC + c4 * 4];
            float4 v;
            v.x = w0 * f0.x + w1 * f1.x + w2 * f2.x;
            v.y = w0 * f0.y + w1 * f1.y + w2 * f2.y;
            v.z = w0 * f0.z + w1 * f1.z + w2 * f2.z;
            v.w = w0 * f0.w + w1 * f1.w + w2 * f2.w;
            unsigned* dst = (unsigned*)&xa[r][0];
            dst[c4 * 2 + 0] = bf16pair(v.x, v.y);
            dst[c4 * 2 + 1] = bf16pair(v.z, v.w);
        }
    } else {
        const ushort_t* Xbf = (const ushort_t*)Xsrc_;
        // ---- BN prologue: reduce 8-group stats -> scale/shift in LDS ----
        if (threadIdx.x < CC) {
            const int c = threadIdx.x;
            float s = 0.f, q = 0.f;
#pragma unroll
            for (int gr = 0; gr < NGRP; ++gr) {
                s += statsIn[gr * 256 + c];
                q += statsIn[gr * 256 + CC + c];
            }
            const float m = s * (1.f / (float)NQ);
            const float v = fmaf(-m, m, q * (1.f / (float)NQ));
            const float rstd = rsqrtf(v + EPS_BN);
            const float scl = gIn[c] * rstd;
            sc_l[c] = scl;
            sh_l[c] = fmaf(-m, scl, beIn[c]);
            if (threadIdx.x < NCT * 16) { blk_s[threadIdx.x] = 0.f; blk_q[threadIdx.x] = 0.f; }
        }
        __syncthreads();
        // X staging: uint4 = 8 bf16 per iter, 4 iters/thread
#pragma unroll
        for (int e = threadIdx.x; e < 64 * 16; e += 256) {
            const int r = e >> 4, c8 = e & 15;
            const uint4 u = *(const uint4*)&Xbf[(size_t)(row0 + r) * CC + c8 * 8];
            const float4 s0 = *(const float4*)&sc_l[c8 * 8];
            const float4 s1 = *(const float4*)&sc_l[c8 * 8 + 4];
            const float4 h0 = *(const float4*)&sh_l[c8 * 8];
            const float4 h1 = *(const float4*)&sh_l[c8 * 8 + 4];
            const float v0 = fmaxf(fmaf(bflo(u.x), s0.x, h0.x), 0.f);
            const float v1 = fmaxf(fmaf(bfhi(u.x), s0.y, h0.y), 0.f);
            const float v2 = fmaxf(fmaf(bflo(u.y), s0.z, h0.z), 0.f);
            const float v3 = fmaxf(fmaf(bfhi(u.y), s0.w, h0.w), 0.f);
            const float v4 = fmaxf(fmaf(bflo(u.z), s1.x, h1.x), 0.f);
            const float v5 = fmaxf(fmaf(bfhi(u.z), s1.y, h1.y), 0.f);
            const float v6 = fmaxf(fmaf(bflo(u.w), s1.z, h1.z), 0.f);
            const float v7 = fmaxf(fmaf(bfhi(u.w), s1.w, h1.w), 0.f);
            uint4 o;
            o.x = bf16pair(v0, v1); o.y = bf16pair(v2, v3);
            o.z = bf16pair(v4, v5); o.w = bf16pair(v6, v7);
            *(uint4*)&xa[r][c8 * 8] = o;
        }
    }
    // ---- W tile staging: pre-converted bf16, 16B copies ----
#pragma unroll
    for (int e = threadIdx.x; e < NCT * 16 * 16; e += 256) {
        const int co = e >> 4, seg = e & 15;
        *(float4*)&wb[co][seg * 8] = *(const float4*)&Wb[(size_t)(colbase + co) * CC + seg * 8];
    }
    __syncthreads();

    const int lane = threadIdx.x & 63;
    const int wv = threadIdx.x >> 6;     // wave -> rows 16*wv..+15
    const int nn = lane & 15;
    const int quad = lane >> 4;

    floatx4 acc[NCT] = {};

    const short* arow = &xa[wv * 16 + nn][0];
#pragma unroll
    for (int ks = 0; ks < 4; ++ks) {
        const bf16x8 a = *(const bf16x8*)(arow + ks * 32 + quad * 8);
#pragma unroll
        for (int ct = 0; ct < NCT; ++ct) {
            const bf16x8 b = *(const bf16x8*)(&wb[ct * 16 + nn][0] + ks * 32 + quad * 8);
            acc[ct] = __builtin_amdgcn_mfma_f32_16x16x32_bf16(a, b, acc[ct], 0, 0, 0);
        }
    }

    // ---- epilogue: bias, bf16 Y store, column stats (fp32) ----
#pragma unroll
    for (int ct = 0; ct < NCT; ++ct) {
        const float bv = bias[colbase + ct * 16 + nn];
        float s = 0.f, qv = 0.f;
#pragma unroll
        for (int r = 0; r < 4; ++r) {
            acc[ct][r] += bv;
            s += acc[ct][r];
            qv = fmaf(acc[ct][r], acc[ct][r], qv);
        }
#pragma unroll
        for (int r = 0; r < 4; ++r)
            Y[(size_t)(row0 + wv * 16 + quad * 4 + r) * CC + colbase + ct * 16 + nn] = bf16one(acc[ct][r]);
        s += __shfl_xor(s, 16, 64); s += __shfl_xor(s, 32, 64);
        qv += __shfl_xor(qv, 16, 64); qv += __shfl_xor(qv, 32, 64);
        if (quad == 0) {
            atomicAdd(&blk_s[ct * 16 + nn], s);
            atomicAdd(&blk_q[ct * 16 + nn], qv);
        }
    }
    __syncthreads();
    // 8-group global stats: low-contention atomicAdd (keyed by row-block)
    {
        const int gr = rb & (NGRP - 1);
        const int ch = threadIdx.x;
        if (ch < NCT * 16)
            atomicAdd(&statsOut[gr * 256 + colbase + ch], blk_s[ch]);
        else if (ch < 2 * NCT * 16)
            atomicAdd(&statsOut[gr * 256 + CC + colbase + (ch - NCT * 16)], blk_q[ch - NCT * 16]);
    }
}

// ---------------------------------------------------------------------------
// Final BN + ReLU with in-kernel stats reduce; bf16 in, fp32 out.
// grid = 1024 x 256; each thread handles 2 x 8 elements.
// ---------------------------------------------------------------------------
__global__ __launch_bounds__(256) void bn_final(const ushort_t* __restrict__ Y,
                                                const float* __restrict__ statsIn,
                                                const float* __restrict__ g,
                                                const float* __restrict__ be,
                                                float* __restrict__ out) {
    __shared__ float sc_l[CC], sh_l[CC];
    if (threadIdx.x < CC) {
        const int c = threadIdx.x;
        float s = 0.f, q = 0.f;
#pragma unroll
        for (int gr = 0; gr < NGRP; ++gr) {
            s += statsIn[gr * 256 + c];
            q += statsIn[gr * 256 + CC + c];
        }
        const float m = s * (1.f / (float)NQ);
        const float v = fmaf(-m, m, q * (1.f / (float)NQ));
        const float rstd = rsqrtf(v + EPS_BN);
        const float scl = g[c] * rstd;
        sc_l[c] = scl;
        sh_l[c] = fmaf(-m, scl, be[c]);
    }
    __syncthreads();
    const int base = blockIdx.x * 512 + threadIdx.x;   // 8-col group index
#pragma unroll
    for (int it = 0; it < 2; ++it) {
        const int i8 = base + it * 256;
        const int c8 = (i8 & 15) * 8;
        const uint4 u = *(const uint4*)&Y[(size_t)i8 * 8];
        const float4 s0 = *(const float4*)&sc_l[c8];
        const float4 s1 = *(const float4*)&sc_l[c8 + 4];
        const float4 h0 = *(const float4*)&sh_l[c8];
        const float4 h1 = *(const float4*)&sh_l[c8 + 4];
        float4 o0, o1;
        o0.x = fmaxf(fmaf(bflo(u.x), s0.x, h0.x), 0.f);
        o0.y = fmaxf(fmaf(bfhi(u.x), s0.y, h0.y), 0.f);
        o0.z = fmaxf(fmaf(bflo(u.y), s0.z, h0.z), 0.f);
        o0.w = fmaxf(fmaf(bfhi(u.y), s0.w, h0.w), 0.f);
        o1.x = fmaxf(fmaf(bflo(u.z), s1.x, h1.x), 0.f);
        o1.y = fmaxf(fmaf(bfhi(u.z), s1.y, h1.y), 0.f);
        o1.z = fmaxf(fmaf(bflo(u.w), s1.z, h1.z), 0.f);
        o1.w = fmaxf(fmaf(bfhi(u.w), s1.w, h1.w), 0.f);
        ((float4*)out)[i8 * 2 + 0] = o0;
        ((float4*)out)[i8 * 2 + 1] = o1;
    }
}

// ---------------------------------------------------------------------------
extern "C" void kernel_launch(void* const* d_in, const int* in_sizes, int n_in,
                              void* d_out, int out_size, void* d_ws, size_t ws_size,
                              hipStream_t stream) {
    (void)in_sizes; (void)n_in; (void)out_size; (void)ws_size;

    const float* pos1  = (const float*)d_in[0];
    const float* pos2  = (const float*)d_in[1];
    const float* feat2 = (const float*)d_in[2];
    const float* Wl[3]  = {(const float*)d_in[3], (const float*)d_in[7],  (const float*)d_in[11]};
    const float* bl[3]  = {(const float*)d_in[4], (const float*)d_in[8],  (const float*)d_in[12]};
    const float* gl[3]  = {(const float*)d_in[5], (const float*)d_in[9],  (const float*)d_in[13]};
    const float* bel[3] = {(const float*)d_in[6], (const float*)d_in[10], (const float*)d_in[14]};

    // Workspace layout
    float* ws = (float*)d_ws;
    ushort_t* B0 = (ushort_t*)ws;                   // NQ*CC bf16 (8 MB)
    ushort_t* B1 = B0 + (size_t)NQ * CC;            // NQ*CC bf16 (8 MB)
    unsigned* skeys = (unsigned*)(B1 + (size_t)NQ * CC);   // NQ*48 u32 (6 MB)
    float* stats = (float*)(skeys + (size_t)NQ * NSURV);   // 3*NGRP*256 floats
    ushort_t* Wbf = (ushort_t*)(stats + 3 * NGRP * 256);   // 3*16384 bf16
    float4* pos2pk = (float4*)(Wbf + 3 * CC * CC);         // (MC+16)*16 B

    float* st0 = stats + 0 * NGRP * 256;
    float* st1 = stats + 1 * NGRP * 256;
    float* st2 = stats + 2 * NGRP * 256;

    // 0: pack pos2 -> {x,y,z,0.5|c|^2} (+pad; must precede knn scan)
    pack_kernel<<<8, TB, 0, stream>>>(pos2, pos2pk);
    // 1: KNN scan (4-deep pipelined SGPR stream) + W bf16 prep + stats zero
    knn_kernel<<<KNN_B + 16, TB, 0, stream>>>(pos1, pos2pk, skeys,
                                              Wl[0], Wl[1], Wl[2], Wbf, stats);
    // 2: layer 0 (rerank + interp fused) -> B0 (bf16), st0
    gemm_mfma<0, 1><<<GEMM_B, 256, 0, stream>>>(feat2, skeys, pos1, pos2,
                                                nullptr, nullptr, nullptr,
                                                Wbf + 0 * CC * CC, bl[0], B0, st0);
    // 3: layer 1 (stats-reduce + BN fused, col-split x2) -> B1 (bf16), st1
    gemm_mfma<1, 2><<<GEMM_B * 2, 256, 0, stream>>>(B0, nullptr, nullptr, nullptr,
                                                    st0, gl[0], bel[0],
                                                    Wbf + 1 * CC * CC, bl[1], B1, st1);
    // 4: layer 2 (col-split x2) -> B0 (bf16), st2
    gemm_mfma<1, 2><<<GEMM_B * 2, 256, 0, stream>>>(B1, nullptr, nullptr, nullptr,
                                                    st1, gl[1], bel[1],
                                                    Wbf + 2 * CC * CC, bl[2], B0, st2);
    // 5: final BN+ReLU (stats-reduce fused) -> out (fp32)
    bn_final<<<GEMM_B * 2, 256, 0, stream>>>(B0, st2, gl[2], bel[2], (float*)d_out);
}

// Round 5
// 201.399 us; speedup vs baseline: 1.0528x; 1.0528x over previous
//
#include <hip/hip_runtime.h>
#include <hip/hip_fp16.h>
#include <math.h>

// Problem constants (from reference)
#define NQ 32768   // query points (pos1)
#define MC 8192    // source points (pos2)
#define CC 128     // channels
#define EPS_BN 1e-5f
#define EPS_D  1e-8

#define DBL_BIG 1e300
#define IDX_BIG 0x7fffffff

// KNN config (R11: MFMA distance tiles, split-f16 encoding, med3 top-3)
#define QB  64          // queries per block (16 per wave x 4 waves)
#define TB  256         // threads per block (4 waves)
#define NTIL 256        // 16-candidate tiles per half (4096 cands / 16)
#define KMASK 0xFFFFE000u   // keep sign+exp+10 mantissa bits
#define IMASK 0x1FFFu       // 13-bit index (M=8192)
#define NSURV 24            // survivors per query (2 halves x 4 groups x 3)
#define KNN_B ((NQ / QB) * 2)   // 1024 scan blocks
#define GEMM_B (NQ / 64)        // 512
#define NGRP 8                  // stats atomic groups (2048 addresses)

typedef __attribute__((ext_vector_type(8))) short bf16x8;    // 8 bf16 (4 VGPRs)
typedef __attribute__((ext_vector_type(8))) _Float16 half8;  // 8 f16  (4 VGPRs)
typedef __attribute__((ext_vector_type(4))) float floatx4;   // MFMA accumulator
typedef unsigned short ushort_t;

// RNE fp32 -> bf16 pair packed in u32 (lo = a, hi = b)
__device__ __forceinline__ unsigned bf16pair(float a, float b) {
    unsigned ua = __float_as_uint(a); ua = (ua + 0x7FFFu + ((ua >> 16) & 1u)) >> 16;
    unsigned ub = __float_as_uint(b); ub = (ub + 0x7FFFu + ((ub >> 16) & 1u)) >> 16;
    return ua | (ub << 16);
}
__device__ __forceinline__ ushort_t bf16one(float a) {
    unsigned ua = __float_as_uint(a);
    return (ushort_t)((ua + 0x7FFFu + ((ua >> 16) & 1u)) >> 16);
}
// unpack u32 = (lo bf16, hi bf16) -> 2 fp32
__device__ __forceinline__ float bflo(unsigned u) { return __uint_as_float(u << 16); }
__device__ __forceinline__ float bfhi(unsigned u) { return __uint_as_float(u & 0xFFFF0000u); }

// Branchless insert of x into ascending top-3 (k0<=k1<=k2):
// 1x v_min_f32 + 2x v_med3_f32.
__device__ __forceinline__ void ins3(float& k0, float& k1, float& k2, float x) {
    const float n0 = fminf(k0, x);
    const float n1 = __builtin_amdgcn_fmed3f(k0, k1, x);
    const float n2 = __builtin_amdgcn_fmed3f(k1, k2, x);
    k0 = n0; k1 = n1; k2 = n2;
}

#define PK2(a, b) ((unsigned)__half_as_ushort(a) | ((unsigned)__half_as_ushort(b) << 16))

// ---------------------------------------------------------------------------
// Pack pos2 -> MFMA A-fragment tiles of split-f16 extended vectors.
// Candidate c: ch = f16(c), cl = f16(c - ch); hc = 0.5|ch+cl|^2 (fp64) split
// to f16 pair. Ext A vector (16 slots):
//   [chx,chy,chz, clx,cly,clz, chx,chy,chz, clx,cly,clz, hchi,hclo, 1, 1]
// Tile t, lane slot h*16+m (h = k-half, m = cand row): uint4 at
// ptile[t*32 + h*16 + m]. Buffer = 512 tiles + 2 overshoot-pad tiles.
// ---------------------------------------------------------------------------
__global__ __launch_bounds__(TB) void pack_kernel(const float* __restrict__ pos2,
                                                  uint4* __restrict__ ptile) {
    const int c = blockIdx.x * TB + threadIdx.x;   // grid 32 x 256 = 8192
    const float x = pos2[c * 3 + 0];
    const float y = pos2[c * 3 + 1];
    const float z = pos2[c * 3 + 2];
    const __half chx = __float2half(x); const float fchx = __half2float(chx);
    const __half chy = __float2half(y); const float fchy = __half2float(chy);
    const __half chz = __float2half(z); const float fchz = __half2float(chz);
    const __half clx = __float2half(x - fchx);
    const __half cly = __float2half(y - fchy);
    const __half clz = __float2half(z - fchz);
    const double X = (double)fchx + (double)__half2float(clx);
    const double Y = (double)fchy + (double)__half2float(cly);
    const double Z = (double)fchz + (double)__half2float(clz);
    const double hc = 0.5 * (X * X + Y * Y + Z * Z);
    const __half hchi = __float2half((float)hc);
    const __half hclo = __float2half((float)(hc - (double)__half2float(hchi)));
    const __half one = __float2half(1.0f);
    uint4 a0, a1;
    a0.x = PK2(chx, chy); a0.y = PK2(chz, clx); a0.z = PK2(cly, clz); a0.w = PK2(chx, chy);
    a1.x = PK2(chz, clx); a1.y = PK2(cly, clz); a1.z = PK2(hchi, hclo); a1.w = PK2(one, one);
    const int t = c >> 4, m = c & 15;
    ptile[(size_t)t * 32 + m]      = a0;   // k 0..7
    ptile[(size_t)t * 32 + 16 + m] = a1;   // k 8..15
}

// ---------------------------------------------------------------------------
// KNN scan (MFMA) + piggy-backed weight conversion + stats zero.
// Blocks [0, KNN_B): 64 queries x half of M. Each wave: 16 queries (B cols,
//   fixed frag) x 256 candidate tiles (A frags streamed from L2, 2-deep
//   vmcnt pipeline). One mfma_f32_16x16x32_f16 per tile = 256 exact-to-2e-6
//   0.5*d^2 values; each lane keys its 4 values (bfi idx into KMASK-truncated
//   float) and maintains ascending top-3 via min+med3. No LDS in main loop.
// Blocks [KNN_B, KNN_B+16): convert W0/W1/W2 fp32 -> bf16; first also zeroes
//   stats.
// ---------------------------------------------------------------------------
__global__ __launch_bounds__(TB) void knn_kernel(const float* __restrict__ pos1,
                                                 const uint4* __restrict__ ptile,
                                                 unsigned* __restrict__ skeys,
                                                 const float* __restrict__ W0,
                                                 const float* __restrict__ W1,
                                                 const float* __restrict__ W2,
                                                 ushort_t* __restrict__ Wbf,
                                                 float* __restrict__ stats) {
    __shared__ __align__(16) ushort_t qext[QB][16];   // 2 KB query ext vectors

    if (blockIdx.x >= KNN_B) {                 // ---- prep blocks ----
        const int pb = blockIdx.x - KNN_B;     // 0..15
        const int f = pb * TB + threadIdx.x;   // float4 index within a layer
        const float* Ws[3] = {W0, W1, W2};
#pragma unroll
        for (int l = 0; l < 3; ++l) {
            const float4 v = ((const float4*)Ws[l])[f];
            unsigned* dst = (unsigned*)(Wbf + (size_t)l * CC * CC);
            dst[f * 2 + 0] = bf16pair(v.x, v.y);
            dst[f * 2 + 1] = bf16pair(v.z, v.w);
        }
        if (pb == 0)
            for (int i = threadIdx.x; i < 3 * NGRP * 256; i += TB) stats[i] = 0.f;
        return;
    }

    const int half = blockIdx.x & 1;
    const int bq   = blockIdx.x >> 1;

    // ---- query ext staging: thread i builds query (bq*64+i)'s B vector ----
    // B (16 slots): [-ph x3, -ph x3, -pl x3, -pl x3, 1, 1, hphi, hplo]
    if (threadIdx.x < QB) {
        const int qq = bq * QB + threadIdx.x;
        const float x = pos1[qq * 3 + 0];
        const float y = pos1[qq * 3 + 1];
        const float z = pos1[qq * 3 + 2];
        const __half phx = __float2half(x); const float fphx = __half2float(phx);
        const __half phy = __float2half(y); const float fphy = __half2float(phy);
        const __half phz = __float2half(z); const float fphz = __half2float(phz);
        const __half plx = __float2half(x - fphx);
        const __half ply = __float2half(y - fphy);
        const __half plz = __float2half(z - fphz);
        const double X = (double)fphx + (double)__half2float(plx);
        const double Y = (double)fphy + (double)__half2float(ply);
        const double Z = (double)fphz + (double)__half2float(plz);
        const double hp = 0.5 * (X * X + Y * Y + Z * Z);
        const __half hphi = __float2half((float)hp);
        const __half hplo = __float2half((float)(hp - (double)__half2float(hphi)));
        const ushort_t SG = 0x8000u;   // f16 sign flip = exact negation
        const ushort_t nx = (ushort_t)(__half_as_ushort(phx) ^ SG);
        const ushort_t ny = (ushort_t)(__half_as_ushort(phy) ^ SG);
        const ushort_t nz = (ushort_t)(__half_as_ushort(phz) ^ SG);
        const ushort_t mx = (ushort_t)(__half_as_ushort(plx) ^ SG);
        const ushort_t my = (ushort_t)(__half_as_ushort(ply) ^ SG);
        const ushort_t mz = (ushort_t)(__half_as_ushort(plz) ^ SG);
        const ushort_t on = __half_as_ushort(__float2half(1.0f));
        ushort_t* e = &qext[threadIdx.x][0];
        e[0] = nx; e[1] = ny; e[2] = nz; e[3] = nx; e[4]  = ny; e[5]  = nz;
        e[6] = mx; e[7] = my; e[8] = mz; e[9] = mx; e[10] = my; e[11] = mz;
        e[12] = on; e[13] = on;
        e[14] = __half_as_ushort(hphi); e[15] = __half_as_ushort(hplo);
    }
    __syncthreads();

    const int lane = threadIdx.x & 63;
    const int wv   = threadIdx.x >> 6;   // wave -> queries wv*16..+15
    const int cc   = lane & 15;          // query column
    const int g    = lane >> 4;          // quad: k-slice / candidate-row group

    // B fragment: lane supplies k-slice g*8..+8 of query cc; zero for g>=2
    uint4 bqu = {0u, 0u, 0u, 0u};
    if (g < 2) bqu = *(const uint4*)&qext[wv * 16 + cc][g * 8];
    const half8 bqh = *(const half8*)&bqu;

    // A stream: lane reads slot (g&1)*16+cc of each tile (quads 2,3 mirror
    // 0,1 -- their k16-31 products hit zero B slots, so values are don't-care)
    const uint4* lp = ptile + (size_t)(half * NTIL) * 32 + ((g & 1) * 16 + cc);
#define LD(t) lp[(size_t)(t) * 32]

    const float KINIT = __uint_as_float(0x7F000000u);   // large finite sentinel
    float k0 = KINIT, k1 = KINIT, k2 = KINIT;
    // candidate index regs for this lane's 4 output rows (row = g*4 + r)
    unsigned j0 = (unsigned)(half * 4096 + g * 4 + 0);
    unsigned j1 = j0 + 1, j2 = j0 + 2, j3 = j0 + 3;
    const floatx4 zc = {0.f, 0.f, 0.f, 0.f};

#define KEYS(d) { \
        unsigned u0 = (__float_as_uint(d[0]) & KMASK) | (j0 & ~KMASK); \
        unsigned u1 = (__float_as_uint(d[1]) & KMASK) | (j1 & ~KMASK); \
        unsigned u2 = (__float_as_uint(d[2]) & KMASK) | (j2 & ~KMASK); \
        unsigned u3 = (__float_as_uint(d[3]) & KMASK) | (j3 & ~KMASK); \
        ins3(k0, k1, k2, __uint_as_float(u0)); \
        ins3(k0, k1, k2, __uint_as_float(u1)); \
        ins3(k0, k1, k2, __uint_as_float(u2)); \
        ins3(k0, k1, k2, __uint_as_float(u3)); \
        j0 += 16; j1 += 16; j2 += 16; j3 += 16; }

    uint4 afA = LD(0);
    uint4 afB = LD(1);
    for (int t = 0; t < NTIL; t += 2) {
        const uint4 nA = LD(t + 2);   // overshoots into pad tiles (never consumed)
        const floatx4 dA = __builtin_amdgcn_mfma_f32_16x16x32_f16(*(const half8*)&afA, bqh, zc, 0, 0, 0);
        KEYS(dA);
        const uint4 nB = LD(t + 3);
        const floatx4 dB = __builtin_amdgcn_mfma_f32_16x16x32_f16(*(const half8*)&afB, bqh, zc, 0, 0, 0);
        KEYS(dB);
        afA = nA; afB = nB;
    }
#undef LD
#undef KEYS

    // dump: query q's survivors at skeys[q*24 + half*12 + g*3 + {0,1,2}]
    {
        const int q = bq * QB + wv * 16 + cc;
        unsigned* dst = skeys + (size_t)q * NSURV + half * 12 + g * 3;
        dst[0] = __float_as_uint(k0);
        dst[1] = __float_as_uint(k1);
        dst[2] = __float_as_uint(k2);
    }
}

// ---------------------------------------------------------------------------
// bf16-MFMA fused layer GEMM: Y = Xin @ W^T + bias (fp32 accumulate).
//   MODE 0: prologue re-ranks this block's own 64 queries (fp64 exact) from
//           skeys, then Xin = interp(feat2(fp32), idx, w). Y out: bf16.
//   MODE 1: prologue reduces statsIn[8][256] -> BN scale/shift in LDS, then
//           Xin = relu(Xbf16 * sc[c] + sh[c]). Y out: bf16.
// grid = 512, block = 256.
// ---------------------------------------------------------------------------
template <int MODE>
__global__ __launch_bounds__(256) void gemm_mfma(const void* __restrict__ Xsrc_,
                                                 const unsigned* __restrict__ skeys,
                                                 const float* __restrict__ pos1,
                                                 const float* __restrict__ pos2,
                                                 const float* __restrict__ statsIn,
                                                 const float* __restrict__ gIn,
                                                 const float* __restrict__ beIn,
                                                 const ushort_t* __restrict__ Wb,
                                                 const float* __restrict__ bias,
                                                 ushort_t* __restrict__ Y,
                                                 float* __restrict__ statsOut) {
    __shared__ __align__(16) short xa[64][136];    // 64 rows x 128 k bf16
    __shared__ __align__(16) short wb[128][136];   // 128 co x 128 k bf16
    __shared__ float blk_s[CC], blk_q[CC];         // epilogue stat accumulators
    __shared__ float sc_l[CC], sh_l[CC];           // MODE 1 BN scale/shift

    const int row0 = blockIdx.x * 64;

    // ---- X tile staging (+ fused transform) ----
    if constexpr (MODE == 0) {
        const float* feat2 = (const float*)Xsrc_;
        __shared__ int   lidx[QB][3];
        __shared__ float lw[QB][3];
        {   // exact fp64 re-rank of this block's 64 queries; 4 thr/query x 6
            double* rrd = (double*)&xa[0][0];   // [64][4][3] = 6144 B scratch
            int*    rri = (int*)&wb[0][0];      // [64][4][3] = 3072 B scratch
            const int ql = threadIdx.x >> 2;
            const int pp = threadIdx.x & 3;
            const int qg = row0 + ql;
            const double qx = (double)pos1[qg * 3 + 0];
            const double qy = (double)pos1[qg * 3 + 1];
            const double qz = (double)pos1[qg * 3 + 2];
            double b0 = DBL_BIG, b1 = DBL_BIG, b2 = DBL_BIG;
            int    j0 = IDX_BIG, j1 = IDX_BIG, j2 = IDX_BIG;
            const uint2* kp = (const uint2*)(skeys + (size_t)qg * NSURV + pp * 6);
            const uint2 ka = kp[0], kb = kp[1], kc = kp[2];
            const unsigned ks[6] = {ka.x, ka.y, kb.x, kb.y, kc.x, kc.y};
#pragma unroll
            for (int u = 0; u < 6; ++u) {
                const int id = (int)(ks[u] & IMASK);
                const double x = (double)pos2[id * 3 + 0];
                const double y = (double)pos2[id * 3 + 1];
                const double z = (double)pos2[id * 3 + 2];
                const double ax = qx - x, ay = qy - y, az = qz - z;
                const double d = ax * ax + ay * ay + az * az;
                const bool l2 = (d < b2) || (d == b2 && id < j2);
                if (l2) {
                    const bool l1 = (d < b1) || (d == b1 && id < j1);
                    const bool l0 = (d < b0) || (d == b0 && id < j0);
                    b2 = l1 ? b1 : d;              j2 = l1 ? j1 : id;
                    b1 = l1 ? (l0 ? b0 : d) : b1;  j1 = l1 ? (l0 ? j0 : id) : j1;
                    b0 = l0 ? d : b0;              j0 = l0 ? id : j0;
                }
            }
            const int base = (ql * 4 + pp) * 3;
            rrd[base + 0] = b0; rri[base + 0] = j0;
            rrd[base + 1] = b1; rri[base + 1] = j1;
            rrd[base + 2] = b2; rri[base + 2] = j2;
            __syncthreads();
            if (threadIdx.x < QB) {
                const int qq = threadIdx.x;
                double c0 = DBL_BIG, c1 = DBL_BIG, c2 = DBL_BIG;
                int    i0 = IDX_BIG, i1 = IDX_BIG, i2 = IDX_BIG;
#pragma unroll
                for (int s = 0; s < 12; ++s) {
                    const double d = rrd[qq * 12 + s];
                    const int   id = rri[qq * 12 + s];
                    const bool l2 = (d < c2) || (d == c2 && id < i2);
                    if (l2) {
                        const bool l1 = (d < c1) || (d == c1 && id < i1);
                        const bool l0 = (d < c0) || (d == c0 && id < i0);
                        c2 = l1 ? c1 : d;              i2 = l1 ? i1 : id;
                        c1 = l1 ? (l0 ? c0 : d) : c1;  i1 = l1 ? (l0 ? i0 : id) : i1;
                        c0 = l0 ? d : c0;              i0 = l0 ? id : i0;
                    }
                }
                const double r0 = 1.0 / (c0 + EPS_D);
                const double r1 = 1.0 / (c1 + EPS_D);
                const double r2 = 1.0 / (c2 + EPS_D);
                const double inv = 1.0 / (r0 + r1 + r2);
                lidx[qq][0] = i0; lidx[qq][1] = i1; lidx[qq][2] = i2;
                lw[qq][0] = (float)(r0 * inv);
                lw[qq][1] = (float)(r1 * inv);
                lw[qq][2] = (float)(r2 * inv);
            }
            __syncthreads();
        }
        if (threadIdx.x < CC) { blk_s[threadIdx.x] = 0.f; blk_q[threadIdx.x] = 0.f; }
#pragma unroll
        for (int e = threadIdx.x; e < 64 * 32; e += 256) {
            const int r = e >> 5, c4 = e & 31;
            const int i0 = lidx[r][0], i1 = lidx[r][1], i2 = lidx[r][2];
            const float w0 = lw[r][0], w1 = lw[r][1], w2 = lw[r][2];
            const float4 f0 = *(const float4*)&feat2[(size_t)i0 * CC + c4 * 4];
            const float4 f1 = *(const float4*)&feat2[(size_t)i1 * CC + c4 * 4];
            const float4 f2 = *(const float4*)&feat2[(size_t)i2 * CC + c4 * 4];
            float4 v;
            v.x = w0 * f0.x + w1 * f1.x + w2 * f2.x;
            v.y = w0 * f0.y + w1 * f1.y + w2 * f2.y;
            v.z = w0 * f0.z + w1 * f1.z + w2 * f2.z;
            v.w = w0 * f0.w + w1 * f1.w + w2 * f2.w;
            unsigned* dst = (unsigned*)&xa[r][0];
            dst[c4 * 2 + 0] = bf16pair(v.x, v.y);
            dst[c4 * 2 + 1] = bf16pair(v.z, v.w);
        }
    } else {
        const ushort_t* Xbf = (const ushort_t*)Xsrc_;
        // ---- BN prologue: reduce 8-group stats -> scale/shift in LDS ----
        if (threadIdx.x < CC) {
            const int c = threadIdx.x;
            float s = 0.f, q = 0.f;
#pragma unroll
            for (int gr = 0; gr < NGRP; ++gr) {
                s += statsIn[gr * 256 + c];
                q += statsIn[gr * 256 + CC + c];
            }
            const float m = s * (1.f / (float)NQ);
            const float v = fmaf(-m, m, q * (1.f / (float)NQ));
            const float rstd = rsqrtf(v + EPS_BN);
            const float scl = gIn[c] * rstd;
            sc_l[c] = scl;
            sh_l[c] = fmaf(-m, scl, beIn[c]);
            blk_s[c] = 0.f; blk_q[c] = 0.f;
        }
        __syncthreads();
        // X staging: uint4 = 8 bf16 per iter, 4 iters/thread
#pragma unroll
        for (int e = threadIdx.x; e < 64 * 16; e += 256) {
            const int r = e >> 4, c8 = e & 15;
            const uint4 u = *(const uint4*)&Xbf[(size_t)(row0 + r) * CC + c8 * 8];
            const float4 s0 = *(const float4*)&sc_l[c8 * 8];
            const float4 s1 = *(const float4*)&sc_l[c8 * 8 + 4];
            const float4 h0 = *(const float4*)&sh_l[c8 * 8];
            const float4 h1 = *(const float4*)&sh_l[c8 * 8 + 4];
            const float v0 = fmaxf(fmaf(bflo(u.x), s0.x, h0.x), 0.f);
            const float v1 = fmaxf(fmaf(bfhi(u.x), s0.y, h0.y), 0.f);
            const float v2 = fmaxf(fmaf(bflo(u.y), s0.z, h0.z), 0.f);
            const float v3 = fmaxf(fmaf(bfhi(u.y), s0.w, h0.w), 0.f);
            const float v4 = fmaxf(fmaf(bflo(u.z), s1.x, h1.x), 0.f);
            const float v5 = fmaxf(fmaf(bfhi(u.z), s1.y, h1.y), 0.f);
            const float v6 = fmaxf(fmaf(bflo(u.w), s1.z, h1.z), 0.f);
            const float v7 = fmaxf(fmaf(bfhi(u.w), s1.w, h1.w), 0.f);
            uint4 o;
            o.x = bf16pair(v0, v1); o.y = bf16pair(v2, v3);
            o.z = bf16pair(v4, v5); o.w = bf16pair(v6, v7);
            *(uint4*)&xa[r][c8 * 8] = o;
        }
    }
    // ---- W tile staging: pre-converted bf16, 16B copies ----
#pragma unroll
    for (int e = threadIdx.x; e < 128 * 16; e += 256) {
        const int co = e >> 4, seg = e & 15;
        *(float4*)&wb[co][seg * 8] = *(const float4*)&Wb[(size_t)co * CC + seg * 8];
    }
    __syncthreads();

    const int lane = threadIdx.x & 63;
    const int wv = threadIdx.x >> 6;     // wave -> rows 16*wv..+15
    const int nn = lane & 15;
    const int quad = lane >> 4;

    floatx4 acc[8] = {};

    const short* arow = &xa[wv * 16 + nn][0];
#pragma unroll
    for (int ks = 0; ks < 4; ++ks) {
        const bf16x8 a = *(const bf16x8*)(arow + ks * 32 + quad * 8);
#pragma unroll
        for (int ct = 0; ct < 8; ++ct) {
            const bf16x8 b = *(const bf16x8*)(&wb[ct * 16 + nn][0] + ks * 32 + quad * 8);
            acc[ct] = __builtin_amdgcn_mfma_f32_16x16x32_bf16(a, b, acc[ct], 0, 0, 0);
        }
    }

    // ---- epilogue: bias, bf16 Y store, column stats (fp32) ----
#pragma unroll
    for (int ct = 0; ct < 8; ++ct) {
        const float bv = bias[ct * 16 + nn];
        float s = 0.f, qv = 0.f;
#pragma unroll
        for (int r = 0; r < 4; ++r) {
            acc[ct][r] += bv;
            s += acc[ct][r];
            qv = fmaf(acc[ct][r], acc[ct][r], qv);
        }
#pragma unroll
        for (int r = 0; r < 4; ++r)
            Y[(size_t)(row0 + wv * 16 + quad * 4 + r) * CC + ct * 16 + nn] = bf16one(acc[ct][r]);
        s += __shfl_xor(s, 16, 64); s += __shfl_xor(s, 32, 64);
        qv += __shfl_xor(qv, 16, 64); qv += __shfl_xor(qv, 32, 64);
        if (quad == 0) {
            atomicAdd(&blk_s[ct * 16 + nn], s);
            atomicAdd(&blk_q[ct * 16 + nn], qv);
        }
    }
    __syncthreads();
    // 8-group global stats: low-contention atomicAdd (2048 addresses)
    {
        const int ch = threadIdx.x;
        const float v = (ch < CC) ? blk_s[ch] : blk_q[ch - CC];
        atomicAdd(&statsOut[(blockIdx.x & (NGRP - 1)) * 256 + ch], v);
    }
}

// ---------------------------------------------------------------------------
// Final BN + ReLU with in-kernel stats reduce; bf16 in, fp32 out.
// grid = 512 x 256; each thread handles 4 x 8 elements.
// ---------------------------------------------------------------------------
__global__ __launch_bounds__(256) void bn_final(const ushort_t* __restrict__ Y,
                                                const float* __restrict__ statsIn,
                                                const float* __restrict__ g,
                                                const float* __restrict__ be,
                                                float* __restrict__ out) {
    __shared__ float sc_l[CC], sh_l[CC];
    if (threadIdx.x < CC) {
        const int c = threadIdx.x;
        float s = 0.f, q = 0.f;
#pragma unroll
        for (int gr = 0; gr < NGRP; ++gr) {
            s += statsIn[gr * 256 + c];
            q += statsIn[gr * 256 + CC + c];
        }
        const float m = s * (1.f / (float)NQ);
        const float v = fmaf(-m, m, q * (1.f / (float)NQ));
        const float rstd = rsqrtf(v + EPS_BN);
        const float scl = g[c] * rstd;
        sc_l[c] = scl;
        sh_l[c] = fmaf(-m, scl, be[c]);
    }
    __syncthreads();
    const int base = blockIdx.x * 1024 + threadIdx.x;   // 8-col group index
#pragma unroll
    for (int it = 0; it < 4; ++it) {
        const int i8 = base + it * 256;
        const int c8 = (i8 & 15) * 8;
        const uint4 u = *(const uint4*)&Y[(size_t)i8 * 8];
        const float4 s0 = *(const float4*)&sc_l[c8];
        const float4 s1 = *(const float4*)&sc_l[c8 + 4];
        const float4 h0 = *(const float4*)&sh_l[c8];
        const float4 h1 = *(const float4*)&sh_l[c8 + 4];
        float4 o0, o1;
        o0.x = fmaxf(fmaf(bflo(u.x), s0.x, h0.x), 0.f);
        o0.y = fmaxf(fmaf(bfhi(u.x), s0.y, h0.y), 0.f);
        o0.z = fmaxf(fmaf(bflo(u.y), s0.z, h0.z), 0.f);
        o0.w = fmaxf(fmaf(bfhi(u.y), s0.w, h0.w), 0.f);
        o1.x = fmaxf(fmaf(bflo(u.z), s1.x, h1.x), 0.f);
        o1.y = fmaxf(fmaf(bfhi(u.z), s1.y, h1.y), 0.f);
        o1.z = fmaxf(fmaf(bflo(u.w), s1.z, h1.z), 0.f);
        o1.w = fmaxf(fmaf(bfhi(u.w), s1.w, h1.w), 0.f);
        ((float4*)out)[i8 * 2 + 0] = o0;
        ((float4*)out)[i8 * 2 + 1] = o1;
    }
}

// ---------------------------------------------------------------------------
extern "C" void kernel_launch(void* const* d_in, const int* in_sizes, int n_in,
                              void* d_out, int out_size, void* d_ws, size_t ws_size,
                              hipStream_t stream) {
    (void)in_sizes; (void)n_in; (void)out_size; (void)ws_size;

    const float* pos1  = (const float*)d_in[0];
    const float* pos2  = (const float*)d_in[1];
    const float* feat2 = (const float*)d_in[2];
    const float* Wl[3]  = {(const float*)d_in[3], (const float*)d_in[7],  (const float*)d_in[11]};
    const float* bl[3]  = {(const float*)d_in[4], (const float*)d_in[8],  (const float*)d_in[12]};
    const float* gl[3]  = {(const float*)d_in[5], (const float*)d_in[9],  (const float*)d_in[13]};
    const float* bel[3] = {(const float*)d_in[6], (const float*)d_in[10], (const float*)d_in[14]};

    // Workspace layout
    float* ws = (float*)d_ws;
    ushort_t* B0 = (ushort_t*)ws;                   // NQ*CC bf16 (8 MB)
    ushort_t* B1 = B0 + (size_t)NQ * CC;            // NQ*CC bf16 (8 MB)
    unsigned* skeys = (unsigned*)(B1 + (size_t)NQ * CC);   // NQ*24 u32 (3 MB)
    float* stats = (float*)(skeys + (size_t)NQ * NSURV);   // 3*NGRP*256 floats
    ushort_t* Wbf = (ushort_t*)(stats + 3 * NGRP * 256);   // 3*16384 bf16
    uint4* ptile = (uint4*)(Wbf + 3 * CC * CC);            // (512+2)*32 uint4 (257 KB)

    float* st0 = stats + 0 * NGRP * 256;
    float* st1 = stats + 1 * NGRP * 256;
    float* st2 = stats + 2 * NGRP * 256;

    // 0: pack pos2 -> split-f16 MFMA A-fragment tiles (must precede knn scan)
    pack_kernel<<<MC / TB, TB, 0, stream>>>(pos2, ptile);
    // 1: KNN scan (MFMA distance tiles) + W bf16 prep + stats zero
    knn_kernel<<<KNN_B + 16, TB, 0, stream>>>(pos1, ptile, skeys,
                                              Wl[0], Wl[1], Wl[2], Wbf, stats);
    // 2: layer 0 (rerank + interp fused) -> B0 (bf16), st0
    gemm_mfma<0><<<GEMM_B, 256, 0, stream>>>(feat2, skeys, pos1, pos2,
                                             nullptr, nullptr, nullptr,
                                             Wbf + 0 * CC * CC, bl[0], B0, st0);
    // 3: layer 1 (stats-reduce + BN fused) -> B1 (bf16), st1
    gemm_mfma<1><<<GEMM_B, 256, 0, stream>>>(B0, nullptr, nullptr, nullptr,
                                             st0, gl[0], bel[0],
                                             Wbf + 1 * CC * CC, bl[1], B1, st1);
    // 4: layer 2 -> B0 (bf16), st2
    gemm_mfma<1><<<GEMM_B, 256, 0, stream>>>(B1, nullptr, nullptr, nullptr,
                                             st1, gl[1], bel[1],
                                             Wbf + 2 * CC * CC, bl[2], B0, st2);
    // 5: final BN+ReLU (stats-reduce fused) -> out (fp32)
    bn_final<<<GEMM_B, 256, 0, stream>>>(B0, st2, gl[2], bel[2], (float*)d_out);
}

// Round 6
// 193.009 us; speedup vs baseline: 1.0986x; 1.0435x over previous
//
#include <hip/hip_runtime.h>
#include <hip/hip_fp16.h>
#include <math.h>

// Problem constants (from reference)
#define NQ 32768   // query points (pos1)
#define MC 8192    // source points (pos2)
#define CC 128     // channels
#define EPS_BN 1e-5f
#define EPS_D  1e-8

#define DBL_BIG 1e300
#define IDX_BIG 0x7fffffff

// KNN config (R12: 32x32x16 f16 MFMA, K=16 exact, 4-way split sort chains,
// 4 M-pieces x 2 wave-halves)
#define QB  64          // queries per block (2 tiles of 32)
#define TB  256         // threads per block (4 waves)
#define PCE 2048        // piece of M per block
#define NT  32          // 32-cand tiles per wave (1024 cands)
#define KMASK 0xFFFFE000u   // keep sign+exp+10 mantissa bits
#define IMASK 0x1FFFu       // 13-bit index (M=8192)
#define NSURV 48            // survivors/query (4 pieces x 2 wh x 2 h x 3)
#define KNN_B ((NQ / QB) * 4)   // 2048 scan blocks
#define GEMM_B (NQ / 64)        // 512
#define NGRP 8                  // stats atomic groups (2048 addresses)

typedef __attribute__((ext_vector_type(8))) short bf16x8;     // 8 bf16
typedef __attribute__((ext_vector_type(8))) _Float16 half8;   // 8 f16
typedef __attribute__((ext_vector_type(4))) float floatx4;    // 16x16 acc
typedef __attribute__((ext_vector_type(16))) float floatx16;  // 32x32 acc
typedef unsigned short ushort_t;

// RNE fp32 -> bf16 pair packed in u32 (lo = a, hi = b)
__device__ __forceinline__ unsigned bf16pair(float a, float b) {
    unsigned ua = __float_as_uint(a); ua = (ua + 0x7FFFu + ((ua >> 16) & 1u)) >> 16;
    unsigned ub = __float_as_uint(b); ub = (ub + 0x7FFFu + ((ub >> 16) & 1u)) >> 16;
    return ua | (ub << 16);
}
__device__ __forceinline__ ushort_t bf16one(float a) {
    unsigned ua = __float_as_uint(a);
    return (ushort_t)((ua + 0x7FFFu + ((ua >> 16) & 1u)) >> 16);
}
// unpack u32 = (lo bf16, hi bf16) -> 2 fp32
__device__ __forceinline__ float bflo(unsigned u) { return __uint_as_float(u << 16); }
__device__ __forceinline__ float bfhi(unsigned u) { return __uint_as_float(u & 0xFFFF0000u); }

// Branchless insert of x into ascending top-3 (k0<=k1<=k2):
// 1x v_min_f32 + 2x v_med3_f32.
__device__ __forceinline__ void ins3(float& k0, float& k1, float& k2, float x) {
    const float n0 = fminf(k0, x);
    const float n1 = __builtin_amdgcn_fmed3f(k0, k1, x);
    const float n2 = __builtin_amdgcn_fmed3f(k1, k2, x);
    k0 = n0; k1 = n1; k2 = n2;
}

#define PK2(a, b) ((unsigned)__half_as_ushort(a) | ((unsigned)__half_as_ushort(b) << 16))

// ---------------------------------------------------------------------------
// Pack pos2 -> 32x32x16 MFMA A-fragment tiles of split-f16 extended vectors.
// Candidate c: ch = f16(c), cl = f16(c - ch); hc = 0.5|ch+cl|^2 (fp64) split
// to f16 pair. A slots (16): [ch3, cl3, ch3, cl3, hchi, hclo, 1, 1]
// (pairs with B = [-ph3, -ph3, -pl3, -pl3, 1, 1, hphi, hplo] -> sum = 0.5d^2).
// Tile t (32 cands): lane l reads uint4 at t*64 + (l>>5)*32 + (l&31)
// (row = l&31, k-slice = (l>>5)*8). Buffer = 256 tiles + 2 pad tiles.
// ---------------------------------------------------------------------------
__global__ __launch_bounds__(TB) void pack_kernel(const float* __restrict__ pos2,
                                                  uint4* __restrict__ ptile) {
    const int c = blockIdx.x * TB + threadIdx.x;   // grid 32 x 256 = 8192
    const float x = pos2[c * 3 + 0];
    const float y = pos2[c * 3 + 1];
    const float z = pos2[c * 3 + 2];
    const __half chx = __float2half(x); const float fchx = __half2float(chx);
    const __half chy = __float2half(y); const float fchy = __half2float(chy);
    const __half chz = __float2half(z); const float fchz = __half2float(chz);
    const __half clx = __float2half(x - fchx);
    const __half cly = __float2half(y - fchy);
    const __half clz = __float2half(z - fchz);
    const double X = (double)fchx + (double)__half2float(clx);
    const double Y = (double)fchy + (double)__half2float(cly);
    const double Z = (double)fchz + (double)__half2float(clz);
    const double hc = 0.5 * (X * X + Y * Y + Z * Z);
    const __half hchi = __float2half((float)hc);
    const __half hclo = __float2half((float)(hc - (double)__half2float(hchi)));
    const __half one = __float2half(1.0f);
    uint4 a0, a1;
    a0.x = PK2(chx, chy); a0.y = PK2(chz, clx); a0.z = PK2(cly, clz); a0.w = PK2(chx, chy);
    a1.x = PK2(chz, clx); a1.y = PK2(cly, clz); a1.z = PK2(hchi, hclo); a1.w = PK2(one, one);
    const int t = c >> 5, m = c & 31;
    ptile[(size_t)t * 64 + m]      = a0;   // k 0..7
    ptile[(size_t)t * 64 + 32 + m] = a1;   // k 8..15
    if (blockIdx.x == 0 && threadIdx.x < 128) {   // 2 zero pad tiles
        uint4 zf = {0u, 0u, 0u, 0u};
        ptile[(size_t)256 * 64 + threadIdx.x] = zf;
    }
}

// ---------------------------------------------------------------------------
// KNN scan (32x32 MFMA) + piggy-backed weight conversion + stats zero.
// Blocks [0, KNN_B): 64 queries x one quarter of M. Waves {0,1} own query
//   tile 0 (cols 0..31), {2,3} tile 1; within a pair, wave half wh scans
//   1024 cands = 32 tiles. Per tile: 1 load (16B/lane), 1 MFMA (1024 pairs),
//   16 keys into 4 INDEPENDENT top-3 chains (reg-quad = disjoint cand rows),
//   merged (9 ins3) at the end. 2-deep vmcnt prefetch; no LDS in main loop.
// Blocks [KNN_B, KNN_B+16): W fp32 -> bf16 conversion; first zeroes stats.
// ---------------------------------------------------------------------------
__global__ __launch_bounds__(TB) void knn_kernel(const float* __restrict__ pos1,
                                                 const uint4* __restrict__ ptile,
                                                 unsigned* __restrict__ skeys,
                                                 const float* __restrict__ W0,
                                                 const float* __restrict__ W1,
                                                 const float* __restrict__ W2,
                                                 ushort_t* __restrict__ Wbf,
                                                 float* __restrict__ stats) {
    __shared__ __align__(16) ushort_t qext[QB][16];   // 2 KB query ext vectors

    if (blockIdx.x >= KNN_B) {                 // ---- prep blocks ----
        const int pb = blockIdx.x - KNN_B;     // 0..15
        const int f = pb * TB + threadIdx.x;   // float4 index within a layer
        const float* Ws[3] = {W0, W1, W2};
#pragma unroll
        for (int l = 0; l < 3; ++l) {
            const float4 v = ((const float4*)Ws[l])[f];
            unsigned* dst = (unsigned*)(Wbf + (size_t)l * CC * CC);
            dst[f * 2 + 0] = bf16pair(v.x, v.y);
            dst[f * 2 + 1] = bf16pair(v.z, v.w);
        }
        if (pb == 0)
            for (int i = threadIdx.x; i < 3 * NGRP * 256; i += TB) stats[i] = 0.f;
        return;
    }

    const int piece = blockIdx.x & 3;
    const int bq    = blockIdx.x >> 2;

    // ---- query ext staging: thread i builds query (bq*64+i)'s B vector ----
    // B (16 slots): [-ph x3, -ph x3, -pl x3, -pl x3, 1, 1, hphi, hplo]
    if (threadIdx.x < QB) {
        const int qq = bq * QB + threadIdx.x;
        const float x = pos1[qq * 3 + 0];
        const float y = pos1[qq * 3 + 1];
        const float z = pos1[qq * 3 + 2];
        const __half phx = __float2half(x); const float fphx = __half2float(phx);
        const __half phy = __float2half(y); const float fphy = __half2float(phy);
        const __half phz = __float2half(z); const float fphz = __half2float(phz);
        const __half plx = __float2half(x - fphx);
        const __half ply = __float2half(y - fphy);
        const __half plz = __float2half(z - fphz);
        const double X = (double)fphx + (double)__half2float(plx);
        const double Y = (double)fphy + (double)__half2float(ply);
        const double Z = (double)fphz + (double)__half2float(plz);
        const double hp = 0.5 * (X * X + Y * Y + Z * Z);
        const __half hphi = __float2half((float)hp);
        const __half hplo = __float2half((float)(hp - (double)__half2float(hphi)));
        const ushort_t SG = 0x8000u;   // f16 sign flip = exact negation
        const ushort_t nx = (ushort_t)(__half_as_ushort(phx) ^ SG);
        const ushort_t ny = (ushort_t)(__half_as_ushort(phy) ^ SG);
        const ushort_t nz = (ushort_t)(__half_as_ushort(phz) ^ SG);
        const ushort_t mx = (ushort_t)(__half_as_ushort(plx) ^ SG);
        const ushort_t my = (ushort_t)(__half_as_ushort(ply) ^ SG);
        const ushort_t mz = (ushort_t)(__half_as_ushort(plz) ^ SG);
        const ushort_t on = __half_as_ushort(__float2half(1.0f));
        ushort_t* e = &qext[threadIdx.x][0];
        e[0] = nx; e[1] = ny; e[2] = nz; e[3] = nx; e[4]  = ny; e[5]  = nz;
        e[6] = mx; e[7] = my; e[8] = mz; e[9] = mx; e[10] = my; e[11] = mz;
        e[12] = on; e[13] = on;
        e[14] = __half_as_ushort(hphi); e[15] = __half_as_ushort(hplo);
    }
    __syncthreads();

    const int lane = threadIdx.x & 63;
    const int w    = threadIdx.x >> 6;
    const int qt   = w >> 1;            // query tile (0/1)
    const int wh   = w & 1;             // candidate half within piece
    const int col  = lane & 31;         // query column / candidate row
    const int h    = lane >> 5;         // k-slice (0/1)

    // B fragment: query col's ext vector, k-slice h*8..+8
    const uint4 bqu = *(const uint4*)&qext[qt * 32 + col][h * 8];
    const half8 bqh = *(const half8*)&bqu;

    // A stream: lane's fixed slot within each 1KB tile
    const int cw = piece * PCE + wh * 1024;   // wave's candidate base
    const uint4* lp = ptile + (size_t)(cw >> 5) * 64 + h * 32 + col;
#define LD(t) lp[(size_t)(t) * 64]

    const float KINIT = __uint_as_float(0x7F000000u);   // large finite sentinel
    float a0 = KINIT, a1 = KINIT, a2 = KINIT;   // 4 independent top-3 chains
    float b0 = KINIT, b1 = KINIT, b2 = KINIT;
    float c0 = KINIT, c1 = KINIT, c2 = KINIT;
    float d0 = KINIT, d1 = KINIT, d2 = KINIT;
    // per-set candidate index bases (row = (reg&3) + 8*(reg>>2) + 4*h)
    unsigned ja = (unsigned)(cw + 4 * h + 0);
    unsigned jb = (unsigned)(cw + 4 * h + 8);
    unsigned jc = (unsigned)(cw + 4 * h + 16);
    unsigned jd = (unsigned)(cw + 4 * h + 24);
    const floatx16 zc = {0.f,0.f,0.f,0.f,0.f,0.f,0.f,0.f,0.f,0.f,0.f,0.f,0.f,0.f,0.f,0.f};

#define KEY1(v, jj, K0, K1, K2) { \
        const unsigned u_ = (__float_as_uint(v) & KMASK) | ((jj) & ~KMASK); \
        ins3(K0, K1, K2, __uint_as_float(u_)); }
#define KEYS(d) { \
        KEY1(d[0],  ja,     a0, a1, a2); KEY1(d[1],  ja + 1, a0, a1, a2); \
        KEY1(d[2],  ja + 2, a0, a1, a2); KEY1(d[3],  ja + 3, a0, a1, a2); \
        KEY1(d[4],  jb,     b0, b1, b2); KEY1(d[5],  jb + 1, b0, b1, b2); \
        KEY1(d[6],  jb + 2, b0, b1, b2); KEY1(d[7],  jb + 3, b0, b1, b2); \
        KEY1(d[8],  jc,     c0, c1, c2); KEY1(d[9],  jc + 1, c0, c1, c2); \
        KEY1(d[10], jc + 2, c0, c1, c2); KEY1(d[11], jc + 3, c0, c1, c2); \
        KEY1(d[12], jd,     d0, d1, d2); KEY1(d[13], jd + 1, d0, d1, d2); \
        KEY1(d[14], jd + 2, d0, d1, d2); KEY1(d[15], jd + 3, d0, d1, d2); \
        ja += 32; jb += 32; jc += 32; jd += 32; }

    uint4 fA = LD(0);
    uint4 fB = LD(1);
    floatx16 dA = __builtin_amdgcn_mfma_f32_32x32x16_f16(*(const half8*)&fA, bqh, zc, 0, 0, 0);
    for (int t = 0; t < NT; t += 2) {
        fA = LD(t + 2);   // overshoots into pad tiles on last iter (never consumed)
        const floatx16 dB = __builtin_amdgcn_mfma_f32_32x32x16_f16(*(const half8*)&fB, bqh, zc, 0, 0, 0);
        KEYS(dA);
        fB = LD(t + 3);
        dA = __builtin_amdgcn_mfma_f32_32x32x16_f16(*(const half8*)&fA, bqh, zc, 0, 0, 0);
        KEYS(dB);
    }
#undef LD
#undef KEYS
#undef KEY1

    // merge 4 chains -> one top-3
    ins3(a0, a1, a2, b0); ins3(a0, a1, a2, b1); ins3(a0, a1, a2, b2);
    ins3(a0, a1, a2, c0); ins3(a0, a1, a2, c1); ins3(a0, a1, a2, c2);
    ins3(a0, a1, a2, d0); ins3(a0, a1, a2, d1); ins3(a0, a1, a2, d2);

    // dump: query q's survivors at skeys[q*48 + piece*12 + wh*6 + h*3 + slot]
    {
        const int q = bq * QB + qt * 32 + col;
        unsigned* dst = skeys + (size_t)q * NSURV + piece * 12 + wh * 6 + h * 3;
        dst[0] = __float_as_uint(a0);
        dst[1] = __float_as_uint(a1);
        dst[2] = __float_as_uint(a2);
    }
}

// ---------------------------------------------------------------------------
// bf16-MFMA fused layer GEMM: Y = Xin @ W^T + bias (fp32 accumulate).
//   MODE 0: prologue re-ranks this block's own 64 queries (fp64 exact) from
//           skeys, then Xin = interp(feat2(fp32), idx, w). Y out: bf16.
//   MODE 1: prologue reduces statsIn[8][256] -> BN scale/shift in LDS, then
//           Xin = relu(Xbf16 * sc[c] + sh[c]). Y out: bf16.
// grid = 512, block = 256.
// ---------------------------------------------------------------------------
template <int MODE>
__global__ __launch_bounds__(256) void gemm_mfma(const void* __restrict__ Xsrc_,
                                                 const unsigned* __restrict__ skeys,
                                                 const float* __restrict__ pos1,
                                                 const float* __restrict__ pos2,
                                                 const float* __restrict__ statsIn,
                                                 const float* __restrict__ gIn,
                                                 const float* __restrict__ beIn,
                                                 const ushort_t* __restrict__ Wb,
                                                 const float* __restrict__ bias,
                                                 ushort_t* __restrict__ Y,
                                                 float* __restrict__ statsOut) {
    __shared__ __align__(16) short xa[64][136];    // 64 rows x 128 k bf16
    __shared__ __align__(16) short wb[128][136];   // 128 co x 128 k bf16
    __shared__ float blk_s[CC], blk_q[CC];         // epilogue stat accumulators
    __shared__ float sc_l[CC], sh_l[CC];           // MODE 1 BN scale/shift

    const int row0 = blockIdx.x * 64;

    // ---- X tile staging (+ fused transform) ----
    if constexpr (MODE == 0) {
        const float* feat2 = (const float*)Xsrc_;
        __shared__ int   lidx[QB][3];
        __shared__ float lw[QB][3];
        {   // exact fp64 re-rank of this block's 64 queries; 4 thr/query
            double* rrd = (double*)&xa[0][0];   // [64][4][3] = 6144 B scratch
            int*    rri = (int*)&wb[0][0];      // [64][4][3] = 3072 B scratch
            const int ql = threadIdx.x >> 2;
            const int pp = threadIdx.x & 3;
            const int qg = row0 + ql;
            const double qx = (double)pos1[qg * 3 + 0];
            const double qy = (double)pos1[qg * 3 + 1];
            const double qz = (double)pos1[qg * 3 + 2];
            double b0 = DBL_BIG, b1 = DBL_BIG, b2 = DBL_BIG;
            int    j0 = IDX_BIG, j1 = IDX_BIG, j2 = IDX_BIG;
            const uint4* kp = (const uint4*)(skeys + (size_t)qg * NSURV + pp * 12);
#pragma unroll
            for (int gi = 0; gi < 3; ++gi) {
                const uint4 kk = kp[gi];
                const unsigned ks[4] = {kk.x, kk.y, kk.z, kk.w};
#pragma unroll
                for (int u = 0; u < 4; ++u) {
                    const int id = (int)(ks[u] & IMASK);
                    const double x = (double)pos2[id * 3 + 0];
                    const double y = (double)pos2[id * 3 + 1];
                    const double z = (double)pos2[id * 3 + 2];
                    const double ax = qx - x, ay = qy - y, az = qz - z;
                    const double d = ax * ax + ay * ay + az * az;
                    const bool l2 = (d < b2) || (d == b2 && id < j2);
                    if (l2) {
                        const bool l1 = (d < b1) || (d == b1 && id < j1);
                        const bool l0 = (d < b0) || (d == b0 && id < j0);
                        b2 = l1 ? b1 : d;              j2 = l1 ? j1 : id;
                        b1 = l1 ? (l0 ? b0 : d) : b1;  j1 = l1 ? (l0 ? j0 : id) : j1;
                        b0 = l0 ? d : b0;              j0 = l0 ? id : j0;
                    }
                }
            }
            const int base = (ql * 4 + pp) * 3;
            rrd[base + 0] = b0; rri[base + 0] = j0;
            rrd[base + 1] = b1; rri[base + 1] = j1;
            rrd[base + 2] = b2; rri[base + 2] = j2;
            __syncthreads();
            if (threadIdx.x < QB) {
                const int qq = threadIdx.x;
                double c0 = DBL_BIG, c1 = DBL_BIG, c2 = DBL_BIG;
                int    i0 = IDX_BIG, i1 = IDX_BIG, i2 = IDX_BIG;
#pragma unroll
                for (int s = 0; s < 12; ++s) {
                    const double d = rrd[qq * 12 + s];
                    const int   id = rri[qq * 12 + s];
                    const bool l2 = (d < c2) || (d == c2 && id < i2);
                    if (l2) {
                        const bool l1 = (d < c1) || (d == c1 && id < i1);
                        const bool l0 = (d < c0) || (d == c0 && id < i0);
                        c2 = l1 ? c1 : d;              i2 = l1 ? i1 : id;
                        c1 = l1 ? (l0 ? c0 : d) : c1;  i1 = l1 ? (l0 ? i0 : id) : i1;
                        c0 = l0 ? d : c0;              i0 = l0 ? id : i0;
                    }
                }
                const double r0 = 1.0 / (c0 + EPS_D);
                const double r1 = 1.0 / (c1 + EPS_D);
                const double r2 = 1.0 / (c2 + EPS_D);
                const double inv = 1.0 / (r0 + r1 + r2);
                lidx[qq][0] = i0; lidx[qq][1] = i1; lidx[qq][2] = i2;
                lw[qq][0] = (float)(r0 * inv);
                lw[qq][1] = (float)(r1 * inv);
                lw[qq][2] = (float)(r2 * inv);
            }
            __syncthreads();
        }
        if (threadIdx.x < CC) { blk_s[threadIdx.x] = 0.f; blk_q[threadIdx.x] = 0.f; }
#pragma unroll
        for (int e = threadIdx.x; e < 64 * 32; e += 256) {
            const int r = e >> 5, c4 = e & 31;
            const int i0 = lidx[r][0], i1 = lidx[r][1], i2 = lidx[r][2];
            const float w0 = lw[r][0], w1 = lw[r][1], w2 = lw[r][2];
            const float4 f0 = *(const float4*)&feat2[(size_t)i0 * CC + c4 * 4];
            const float4 f1 = *(const float4*)&feat2[(size_t)i1 * CC + c4 * 4];
            const float4 f2 = *(const float4*)&feat2[(size_t)i2 * CC + c4 * 4];
            float4 v;
            v.x = w0 * f0.x + w1 * f1.x + w2 * f2.x;
            v.y = w0 * f0.y + w1 * f1.y + w2 * f2.y;
            v.z = w0 * f0.z + w1 * f1.z + w2 * f2.z;
            v.w = w0 * f0.w + w1 * f1.w + w2 * f2.w;
            unsigned* dst = (unsigned*)&xa[r][0];
            dst[c4 * 2 + 0] = bf16pair(v.x, v.y);
            dst[c4 * 2 + 1] = bf16pair(v.z, v.w);
        }
    } else {
        const ushort_t* Xbf = (const ushort_t*)Xsrc_;
        // ---- BN prologue: reduce 8-group stats -> scale/shift in LDS ----
        if (threadIdx.x < CC) {
            const int c = threadIdx.x;
            float s = 0.f, q = 0.f;
#pragma unroll
            for (int gr = 0; gr < NGRP; ++gr) {
                s += statsIn[gr * 256 + c];
                q += statsIn[gr * 256 + CC + c];
            }
            const float m = s * (1.f / (float)NQ);
            const float v = fmaf(-m, m, q * (1.f / (float)NQ));
            const float rstd = rsqrtf(v + EPS_BN);
            const float scl = gIn[c] * rstd;
            sc_l[c] = scl;
            sh_l[c] = fmaf(-m, scl, beIn[c]);
            blk_s[c] = 0.f; blk_q[c] = 0.f;
        }
        __syncthreads();
        // X staging: uint4 = 8 bf16 per iter, 4 iters/thread
#pragma unroll
        for (int e = threadIdx.x; e < 64 * 16; e += 256) {
            const int r = e >> 4, c8 = e & 15;
            const uint4 u = *(const uint4*)&Xbf[(size_t)(row0 + r) * CC + c8 * 8];
            const float4 s0 = *(const float4*)&sc_l[c8 * 8];
            const float4 s1 = *(const float4*)&sc_l[c8 * 8 + 4];
            const float4 h0 = *(const float4*)&sh_l[c8 * 8];
            const float4 h1 = *(const float4*)&sh_l[c8 * 8 + 4];
            const float v0 = fmaxf(fmaf(bflo(u.x), s0.x, h0.x), 0.f);
            const float v1 = fmaxf(fmaf(bfhi(u.x), s0.y, h0.y), 0.f);
            const float v2 = fmaxf(fmaf(bflo(u.y), s0.z, h0.z), 0.f);
            const float v3 = fmaxf(fmaf(bfhi(u.y), s0.w, h0.w), 0.f);
            const float v4 = fmaxf(fmaf(bflo(u.z), s1.x, h1.x), 0.f);
            const float v5 = fmaxf(fmaf(bfhi(u.z), s1.y, h1.y), 0.f);
            const float v6 = fmaxf(fmaf(bflo(u.w), s1.z, h1.z), 0.f);
            const float v7 = fmaxf(fmaf(bfhi(u.w), s1.w, h1.w), 0.f);
            uint4 o;
            o.x = bf16pair(v0, v1); o.y = bf16pair(v2, v3);
            o.z = bf16pair(v4, v5); o.w = bf16pair(v6, v7);
            *(uint4*)&xa[r][c8 * 8] = o;
        }
    }
    // ---- W tile staging: pre-converted bf16, 16B copies ----
#pragma unroll
    for (int e = threadIdx.x; e < 128 * 16; e += 256) {
        const int co = e >> 4, seg = e & 15;
        *(float4*)&wb[co][seg * 8] = *(const float4*)&Wb[(size_t)co * CC + seg * 8];
    }
    __syncthreads();

    const int lane = threadIdx.x & 63;
    const int wv = threadIdx.x >> 6;     // wave -> rows 16*wv..+15
    const int nn = lane & 15;
    const int quad = lane >> 4;

    floatx4 acc[8] = {};

    const short* arow = &xa[wv * 16 + nn][0];
#pragma unroll
    for (int ks = 0; ks < 4; ++ks) {
        const bf16x8 a = *(const bf16x8*)(arow + ks * 32 + quad * 8);
#pragma unroll
        for (int ct = 0; ct < 8; ++ct) {
            const bf16x8 b = *(const bf16x8*)(&wb[ct * 16 + nn][0] + ks * 32 + quad * 8);
            acc[ct] = __builtin_amdgcn_mfma_f32_16x16x32_bf16(a, b, acc[ct], 0, 0, 0);
        }
    }

    // ---- epilogue: bias, bf16 Y store, column stats (fp32) ----
#pragma unroll
    for (int ct = 0; ct < 8; ++ct) {
        const float bv = bias[ct * 16 + nn];
        float s = 0.f, qv = 0.f;
#pragma unroll
        for (int r = 0; r < 4; ++r) {
            acc[ct][r] += bv;
            s += acc[ct][r];
            qv = fmaf(acc[ct][r], acc[ct][r], qv);
        }
#pragma unroll
        for (int r = 0; r < 4; ++r)
            Y[(size_t)(row0 + wv * 16 + quad * 4 + r) * CC + ct * 16 + nn] = bf16one(acc[ct][r]);
        s += __shfl_xor(s, 16, 64); s += __shfl_xor(s, 32, 64);
        qv += __shfl_xor(qv, 16, 64); qv += __shfl_xor(qv, 32, 64);
        if (quad == 0) {
            atomicAdd(&blk_s[ct * 16 + nn], s);
            atomicAdd(&blk_q[ct * 16 + nn], qv);
        }
    }
    __syncthreads();
    // 8-group global stats: low-contention atomicAdd (2048 addresses)
    {
        const int ch = threadIdx.x;
        const float v = (ch < CC) ? blk_s[ch] : blk_q[ch - CC];
        atomicAdd(&statsOut[(blockIdx.x & (NGRP - 1)) * 256 + ch], v);
    }
}

// ---------------------------------------------------------------------------
// Final BN + ReLU with in-kernel stats reduce; bf16 in, fp32 out.
// grid = 512 x 256; each thread handles 4 x 8 elements.
// ---------------------------------------------------------------------------
__global__ __launch_bounds__(256) void bn_final(const ushort_t* __restrict__ Y,
                                                const float* __restrict__ statsIn,
                                                const float* __restrict__ g,
                                                const float* __restrict__ be,
                                                float* __restrict__ out) {
    __shared__ float sc_l[CC], sh_l[CC];
    if (threadIdx.x < CC) {
        const int c = threadIdx.x;
        float s = 0.f, q = 0.f;
#pragma unroll
        for (int gr = 0; gr < NGRP; ++gr) {
            s += statsIn[gr * 256 + c];
            q += statsIn[gr * 256 + CC + c];
        }
        const float m = s * (1.f / (float)NQ);
        const float v = fmaf(-m, m, q * (1.f / (float)NQ));
        const float rstd = rsqrtf(v + EPS_BN);
        const float scl = g[c] * rstd;
        sc_l[c] = scl;
        sh_l[c] = fmaf(-m, scl, be[c]);
    }
    __syncthreads();
    const int base = blockIdx.x * 1024 + threadIdx.x;   // 8-col group index
#pragma unroll
    for (int it = 0; it < 4; ++it) {
        const int i8 = base + it * 256;
        const int c8 = (i8 & 15) * 8;
        const uint4 u = *(const uint4*)&Y[(size_t)i8 * 8];
        const float4 s0 = *(const float4*)&sc_l[c8];
        const float4 s1 = *(const float4*)&sc_l[c8 + 4];
        const float4 h0 = *(const float4*)&sh_l[c8];
        const float4 h1 = *(const float4*)&sh_l[c8 + 4];
        float4 o0, o1;
        o0.x = fmaxf(fmaf(bflo(u.x), s0.x, h0.x), 0.f);
        o0.y = fmaxf(fmaf(bfhi(u.x), s0.y, h0.y), 0.f);
        o0.z = fmaxf(fmaf(bflo(u.y), s0.z, h0.z), 0.f);
        o0.w = fmaxf(fmaf(bfhi(u.y), s0.w, h0.w), 0.f);
        o1.x = fmaxf(fmaf(bflo(u.z), s1.x, h1.x), 0.f);
        o1.y = fmaxf(fmaf(bfhi(u.z), s1.y, h1.y), 0.f);
        o1.z = fmaxf(fmaf(bflo(u.w), s1.z, h1.z), 0.f);
        o1.w = fmaxf(fmaf(bfhi(u.w), s1.w, h1.w), 0.f);
        ((float4*)out)[i8 * 2 + 0] = o0;
        ((float4*)out)[i8 * 2 + 1] = o1;
    }
}

// ---------------------------------------------------------------------------
extern "C" void kernel_launch(void* const* d_in, const int* in_sizes, int n_in,
                              void* d_out, int out_size, void* d_ws, size_t ws_size,
                              hipStream_t stream) {
    (void)in_sizes; (void)n_in; (void)out_size; (void)ws_size;

    const float* pos1  = (const float*)d_in[0];
    const float* pos2  = (const float*)d_in[1];
    const float* feat2 = (const float*)d_in[2];
    const float* Wl[3]  = {(const float*)d_in[3], (const float*)d_in[7],  (const float*)d_in[11]};
    const float* bl[3]  = {(const float*)d_in[4], (const float*)d_in[8],  (const float*)d_in[12]};
    const float* gl[3]  = {(const float*)d_in[5], (const float*)d_in[9],  (const float*)d_in[13]};
    const float* bel[3] = {(const float*)d_in[6], (const float*)d_in[10], (const float*)d_in[14]};

    // Workspace layout
    float* ws = (float*)d_ws;
    ushort_t* B0 = (ushort_t*)ws;                   // NQ*CC bf16 (8 MB)
    ushort_t* B1 = B0 + (size_t)NQ * CC;            // NQ*CC bf16 (8 MB)
    unsigned* skeys = (unsigned*)(B1 + (size_t)NQ * CC);   // NQ*48 u32 (6 MB)
    float* stats = (float*)(skeys + (size_t)NQ * NSURV);   // 3*NGRP*256 floats
    ushort_t* Wbf = (ushort_t*)(stats + 3 * NGRP * 256);   // 3*16384 bf16
    uint4* ptile = (uint4*)(Wbf + 3 * CC * CC);            // (256+2)*64 uint4 (264 KB)

    float* st0 = stats + 0 * NGRP * 256;
    float* st1 = stats + 1 * NGRP * 256;
    float* st2 = stats + 2 * NGRP * 256;

    // 0: pack pos2 -> split-f16 32x32x16 A-fragment tiles (precedes knn scan)
    pack_kernel<<<MC / TB, TB, 0, stream>>>(pos2, ptile);
    // 1: KNN scan (32x32 MFMA distance tiles) + W bf16 prep + stats zero
    knn_kernel<<<KNN_B + 16, TB, 0, stream>>>(pos1, ptile, skeys,
                                              Wl[0], Wl[1], Wl[2], Wbf, stats);
    // 2: layer 0 (rerank + interp fused) -> B0 (bf16), st0
    gemm_mfma<0><<<GEMM_B, 256, 0, stream>>>(feat2, skeys, pos1, pos2,
                                             nullptr, nullptr, nullptr,
                                             Wbf + 0 * CC * CC, bl[0], B0, st0);
    // 3: layer 1 (stats-reduce + BN fused) -> B1 (bf16), st1
    gemm_mfma<1><<<GEMM_B, 256, 0, stream>>>(B0, nullptr, nullptr, nullptr,
                                             st0, gl[0], bel[0],
                                             Wbf + 1 * CC * CC, bl[1], B1, st1);
    // 4: layer 2 -> B0 (bf16), st2
    gemm_mfma<1><<<GEMM_B, 256, 0, stream>>>(B1, nullptr, nullptr, nullptr,
                                             st1, gl[1], bel[1],
                                             Wbf + 2 * CC * CC, bl[2], B0, st2);
    // 5: final BN+ReLU (stats-reduce fused) -> out (fp32)
    bn_final<<<GEMM_B, 256, 0, stream>>>(B0, st2, gl[2], bel[2], (float*)d_out);
}

// Round 7
// 190.696 us; speedup vs baseline: 1.1119x; 1.0121x over previous
//
#include <hip/hip_runtime.h>
#include <hip/hip_fp16.h>
#include <math.h>

// Problem constants (from reference)
#define NQ 32768   // query points (pos1)
#define MC 8192    // source points (pos2)
#define CC 128     // channels
#define EPS_BN 1e-5f
#define EPS_D  1e-8

#define DBL_BIG 1e300
#define IDX_BIG 0x7fffffff

// KNN config (R13: 32x32x16 f16 MFMA, 7-bit in-key index (t<<2|r) shared
// across chains, single-d accumulator, end-of-wave decode+merge)
#define QB  64          // queries per block (2 tiles of 32)
#define TB  256         // threads per block (4 waves)
#define PCE 2048        // piece of M per block
#define NT  32          // 32-cand tiles per wave (1024 cands)
#define KM7 0xFFFFFF80u     // scan keys: keep sign+exp+16 mant, low 7 = (t<<2)|r
#define KMASK 0xFFFFE000u   // dump keys: sign+exp+10 mant, low 13 = cand index
#define IMASK 0x1FFFu       // 13-bit index (M=8192)
#define NSURV 48            // survivors/query (4 pieces x 2 wh x 2 h x 3)
#define KNN_B ((NQ / QB) * 4)   // 2048 scan blocks
#define GEMM_B (NQ / 64)        // 512
#define NGRP 8                  // stats atomic groups (2048 addresses)

typedef __attribute__((ext_vector_type(8))) short bf16x8;     // 8 bf16
typedef __attribute__((ext_vector_type(8))) _Float16 half8;   // 8 f16
typedef __attribute__((ext_vector_type(4))) float floatx4;    // 16x16 acc
typedef __attribute__((ext_vector_type(16))) float floatx16;  // 32x32 acc
typedef unsigned short ushort_t;

// RNE fp32 -> bf16 pair packed in u32 (lo = a, hi = b)
__device__ __forceinline__ unsigned bf16pair(float a, float b) {
    unsigned ua = __float_as_uint(a); ua = (ua + 0x7FFFu + ((ua >> 16) & 1u)) >> 16;
    unsigned ub = __float_as_uint(b); ub = (ub + 0x7FFFu + ((ub >> 16) & 1u)) >> 16;
    return ua | (ub << 16);
}
__device__ __forceinline__ ushort_t bf16one(float a) {
    unsigned ua = __float_as_uint(a);
    return (ushort_t)((ua + 0x7FFFu + ((ua >> 16) & 1u)) >> 16);
}
// unpack u32 = (lo bf16, hi bf16) -> 2 fp32
__device__ __forceinline__ float bflo(unsigned u) { return __uint_as_float(u << 16); }
__device__ __forceinline__ float bfhi(unsigned u) { return __uint_as_float(u & 0xFFFF0000u); }

// Branchless insert of x into ascending top-3 (k0<=k1<=k2):
// 1x v_min_f32 + 2x v_med3_f32.
__device__ __forceinline__ void ins3(float& k0, float& k1, float& k2, float x) {
    const float n0 = fminf(k0, x);
    const float n1 = __builtin_amdgcn_fmed3f(k0, k1, x);
    const float n2 = __builtin_amdgcn_fmed3f(k1, k2, x);
    k0 = n0; k1 = n1; k2 = n2;
}

#define PK2(a, b) ((unsigned)__half_as_ushort(a) | ((unsigned)__half_as_ushort(b) << 16))

// ---------------------------------------------------------------------------
// Pack pos2 -> (a) 32x32x16 MFMA A-fragment tiles of split-f16 ext vectors,
//              (b) pos2f4: float4 {x,y,z,0} for the gemm rerank (1 aligned
//                  16B load per candidate instead of 3 scalar random loads).
// A slots (16): [ch3, cl3, ch3, cl3, hchi, hclo, 1, 1]; pairs with
// B = [-ph3, -ph3, -pl3, -pl3, 1, 1, hphi, hplo] -> sum = 0.5d^2.
// Tile t (32 cands): lane l reads uint4 at t*64 + (l>>5)*32 + (l&31).
// ---------------------------------------------------------------------------
__global__ __launch_bounds__(TB) void pack_kernel(const float* __restrict__ pos2,
                                                  uint4* __restrict__ ptile,
                                                  float4* __restrict__ pos2f4) {
    const int c = blockIdx.x * TB + threadIdx.x;   // grid 32 x 256 = 8192
    const float x = pos2[c * 3 + 0];
    const float y = pos2[c * 3 + 1];
    const float z = pos2[c * 3 + 2];
    float4 p4; p4.x = x; p4.y = y; p4.z = z; p4.w = 0.f;
    pos2f4[c] = p4;
    const __half chx = __float2half(x); const float fchx = __half2float(chx);
    const __half chy = __float2half(y); const float fchy = __half2float(chy);
    const __half chz = __float2half(z); const float fchz = __half2float(chz);
    const __half clx = __float2half(x - fchx);
    const __half cly = __float2half(y - fchy);
    const __half clz = __float2half(z - fchz);
    const double X = (double)fchx + (double)__half2float(clx);
    const double Y = (double)fchy + (double)__half2float(cly);
    const double Z = (double)fchz + (double)__half2float(clz);
    const double hc = 0.5 * (X * X + Y * Y + Z * Z);
    const __half hchi = __float2half((float)hc);
    const __half hclo = __float2half((float)(hc - (double)__half2float(hchi)));
    const __half one = __float2half(1.0f);
    uint4 a0, a1;
    a0.x = PK2(chx, chy); a0.y = PK2(chz, clx); a0.z = PK2(cly, clz); a0.w = PK2(chx, chy);
    a1.x = PK2(chz, clx); a1.y = PK2(cly, clz); a1.z = PK2(hchi, hclo); a1.w = PK2(one, one);
    const int t = c >> 5, m = c & 31;
    ptile[(size_t)t * 64 + m]      = a0;   // k 0..7
    ptile[(size_t)t * 64 + 32 + m] = a1;   // k 8..15
    if (blockIdx.x == 0 && threadIdx.x < 128) {   // 2 zero pad tiles
        uint4 zf = {0u, 0u, 0u, 0u};
        ptile[(size_t)256 * 64 + threadIdx.x] = zf;
    }
}

// ---------------------------------------------------------------------------
// KNN scan (32x32 MFMA) + piggy-backed weight conversion + stats zero.
// Blocks [0, KNN_B): 64 queries x one quarter of M. Waves {0,1} own query
//   tile 0 (cols 0..31), {2,3} tile 1; wave half wh scans 1024 cands = 32
//   tiles. Per tile: 1 load (16B/lane), 1 MFMA (1024 pairs), 16 keys
//   (single v_and_or each, 7-bit idx (t<<2)|r shared across the 4 chains)
//   into 4 independent top-3 chains. End of wave: decode 12 survivors to
//   13-bit-idx keys, merge via ins3, dump 3. Single-d accumulator keeps
//   live VGPRs low (avoid AGPR spill + accvgpr_read tax seen in R12).
// Blocks [KNN_B, KNN_B+16): W fp32 -> bf16 conversion; first zeroes stats.
// ---------------------------------------------------------------------------
__global__ __launch_bounds__(TB) void knn_kernel(const float* __restrict__ pos1,
                                                 const uint4* __restrict__ ptile,
                                                 unsigned* __restrict__ skeys,
                                                 const float* __restrict__ W0,
                                                 const float* __restrict__ W1,
                                                 const float* __restrict__ W2,
                                                 ushort_t* __restrict__ Wbf,
                                                 float* __restrict__ stats) {
    __shared__ __align__(16) ushort_t qext[QB][16];   // 2 KB query ext vectors

    if (blockIdx.x >= KNN_B) {                 // ---- prep blocks ----
        const int pb = blockIdx.x - KNN_B;     // 0..15
        const int f = pb * TB + threadIdx.x;   // float4 index within a layer
        const float* Ws[3] = {W0, W1, W2};
#pragma unroll
        for (int l = 0; l < 3; ++l) {
            const float4 v = ((const float4*)Ws[l])[f];
            unsigned* dst = (unsigned*)(Wbf + (size_t)l * CC * CC);
            dst[f * 2 + 0] = bf16pair(v.x, v.y);
            dst[f * 2 + 1] = bf16pair(v.z, v.w);
        }
        if (pb == 0)
            for (int i = threadIdx.x; i < 3 * NGRP * 256; i += TB) stats[i] = 0.f;
        return;
    }

    const int piece = blockIdx.x & 3;
    const int bq    = blockIdx.x >> 2;

    // ---- query ext staging: thread i builds query (bq*64+i)'s B vector ----
    // B (16 slots): [-ph x3, -ph x3, -pl x3, -pl x3, 1, 1, hphi, hplo]
    if (threadIdx.x < QB) {
        const int qq = bq * QB + threadIdx.x;
        const float x = pos1[qq * 3 + 0];
        const float y = pos1[qq * 3 + 1];
        const float z = pos1[qq * 3 + 2];
        const __half phx = __float2half(x); const float fphx = __half2float(phx);
        const __half phy = __float2half(y); const float fphy = __half2float(phy);
        const __half phz = __float2half(z); const float fphz = __half2float(phz);
        const __half plx = __float2half(x - fphx);
        const __half ply = __float2half(y - fphy);
        const __half plz = __float2half(z - fphz);
        const double X = (double)fphx + (double)__half2float(plx);
        const double Y = (double)fphy + (double)__half2float(ply);
        const double Z = (double)fphz + (double)__half2float(plz);
        const double hp = 0.5 * (X * X + Y * Y + Z * Z);
        const __half hphi = __float2half((float)hp);
        const __half hplo = __float2half((float)(hp - (double)__half2float(hphi)));
        const ushort_t SG = 0x8000u;   // f16 sign flip = exact negation
        const ushort_t nx = (ushort_t)(__half_as_ushort(phx) ^ SG);
        const ushort_t ny = (ushort_t)(__half_as_ushort(phy) ^ SG);
        const ushort_t nz = (ushort_t)(__half_as_ushort(phz) ^ SG);
        const ushort_t mx = (ushort_t)(__half_as_ushort(plx) ^ SG);
        const ushort_t my = (ushort_t)(__half_as_ushort(ply) ^ SG);
        const ushort_t mz = (ushort_t)(__half_as_ushort(plz) ^ SG);
        const ushort_t on = __half_as_ushort(__float2half(1.0f));
        ushort_t* e = &qext[threadIdx.x][0];
        e[0] = nx; e[1] = ny; e[2] = nz; e[3] = nx; e[4]  = ny; e[5]  = nz;
        e[6] = mx; e[7] = my; e[8] = mz; e[9] = mx; e[10] = my; e[11] = mz;
        e[12] = on; e[13] = on;
        e[14] = __half_as_ushort(hphi); e[15] = __half_as_ushort(hplo);
    }
    __syncthreads();

    const int lane = threadIdx.x & 63;
    const int w    = threadIdx.x >> 6;
    const int qt   = w >> 1;            // query tile (0/1)
    const int wh   = w & 1;             // candidate half within piece
    const int col  = lane & 31;         // query column / candidate row
    const int h    = lane >> 5;         // k-slice (0/1)

    // B fragment: query col's ext vector, k-slice h*8..+8
    const uint4 bqu = *(const uint4*)&qext[qt * 32 + col][h * 8];
    const half8 bqh = *(const half8*)&bqu;

    // A stream: lane's fixed slot within each 1KB tile
    const int cw = piece * PCE + wh * 1024;   // wave's candidate base
    const uint4* lp = ptile + (size_t)(cw >> 5) * 64 + h * 32 + col;
#define LD(t) lp[(size_t)(t) * 64]

    const float KINIT = __uint_as_float(0x7F000000u);   // large finite sentinel
    float a0 = KINIT, a1 = KINIT, a2 = KINIT;   // 4 independent top-3 chains
    float b0 = KINIT, b1 = KINIT, b2 = KINIT;   // (chain q covers rows 8q+..)
    float c0 = KINIT, c1 = KINIT, c2 = KINIT;
    float e0 = KINIT, e1 = KINIT, e2 = KINIT;
    // shared per-tile index regs: (t<<2)|r, r = reg&3 (same for all chains)
    unsigned i0 = 0u, i1 = 1u, i2 = 2u, i3 = 3u;
    const floatx16 zc = {0.f,0.f,0.f,0.f,0.f,0.f,0.f,0.f,0.f,0.f,0.f,0.f,0.f,0.f,0.f,0.f};

#define KEY1(v, ir, K0, K1, K2) { \
        const unsigned u_ = (__float_as_uint(v) & KM7) | (ir); /* v_and_or_b32 */ \
        ins3(K0, K1, K2, __uint_as_float(u_)); }
#define KEYS(d) { \
        KEY1(d[0],  i0, a0, a1, a2); KEY1(d[1],  i1, a0, a1, a2); \
        KEY1(d[2],  i2, a0, a1, a2); KEY1(d[3],  i3, a0, a1, a2); \
        KEY1(d[4],  i0, b0, b1, b2); KEY1(d[5],  i1, b0, b1, b2); \
        KEY1(d[6],  i2, b0, b1, b2); KEY1(d[7],  i3, b0, b1, b2); \
        KEY1(d[8],  i0, c0, c1, c2); KEY1(d[9],  i1, c0, c1, c2); \
        KEY1(d[10], i2, c0, c1, c2); KEY1(d[11], i3, c0, c1, c2); \
        KEY1(d[12], i0, e0, e1, e2); KEY1(d[13], i1, e0, e1, e2); \
        KEY1(d[14], i2, e0, e1, e2); KEY1(d[15], i3, e0, e1, e2); \
        i0 += 4u; i1 += 4u; i2 += 4u; i3 += 4u; }

    uint4 LA = LD(0);
    uint4 LB = LD(1);
    for (int t = 0; t < NT; t += 2) {
        const floatx16 dv = __builtin_amdgcn_mfma_f32_32x32x16_f16(*(const half8*)&LA, bqh, zc, 0, 0, 0);
        LA = LD(t + 2);   // overshoots into pad tiles on last iter (never consumed)
        KEYS(dv);
        const floatx16 dw = __builtin_amdgcn_mfma_f32_32x32x16_f16(*(const half8*)&LB, bqh, zc, 0, 0, 0);
        LB = LD(t + 3);
        KEYS(dw);
    }
#undef LD
#undef KEYS
#undef KEY1

    // decode chain survivors (7-bit idx -> global cand index, 13-bit key)
    // row = r + 8*chain + 4*h; j = cw + t*32 + row
#define REKEY(kf, q) __uint_as_float((__float_as_uint(kf) & KMASK) | \
        (unsigned)(cw + (int)((__float_as_uint(kf) & 0x7Fu) >> 2) * 32 + \
                   (int)(__float_as_uint(kf) & 3u) + 8 * (q) + 4 * h))
    float m0 = KINIT, m1 = KINIT, m2 = KINIT;
    ins3(m0, m1, m2, REKEY(a0, 0)); ins3(m0, m1, m2, REKEY(a1, 0)); ins3(m0, m1, m2, REKEY(a2, 0));
    ins3(m0, m1, m2, REKEY(b0, 1)); ins3(m0, m1, m2, REKEY(b1, 1)); ins3(m0, m1, m2, REKEY(b2, 1));
    ins3(m0, m1, m2, REKEY(c0, 2)); ins3(m0, m1, m2, REKEY(c1, 2)); ins3(m0, m1, m2, REKEY(c2, 2));
    ins3(m0, m1, m2, REKEY(e0, 3)); ins3(m0, m1, m2, REKEY(e1, 3)); ins3(m0, m1, m2, REKEY(e2, 3));
#undef REKEY

    // dump: query q's survivors at skeys[q*48 + piece*12 + wh*6 + h*3 + slot]
    {
        const int q = bq * QB + qt * 32 + col;
        unsigned* dst = skeys + (size_t)q * NSURV + piece * 12 + wh * 6 + h * 3;
        dst[0] = __float_as_uint(m0);
        dst[1] = __float_as_uint(m1);
        dst[2] = __float_as_uint(m2);
    }
}

// ---------------------------------------------------------------------------
// bf16-MFMA fused layer GEMM: Y = Xin @ W^T + bias (fp32 accumulate).
//   MODE 0: prologue re-ranks this block's own 64 queries (fp64 exact) from
//           skeys (pos2 via packed float4), then Xin = interp(feat2, idx, w).
//   MODE 1: prologue reduces statsIn[8][256] -> BN scale/shift in LDS, then
//           Xin = relu(Xbf16 * sc[c] + sh[c]). Y out: bf16.
// grid = 512, block = 256.
// ---------------------------------------------------------------------------
template <int MODE>
__global__ __launch_bounds__(256) void gemm_mfma(const void* __restrict__ Xsrc_,
                                                 const unsigned* __restrict__ skeys,
                                                 const float* __restrict__ pos1,
                                                 const float4* __restrict__ pos2f4,
                                                 const float* __restrict__ statsIn,
                                                 const float* __restrict__ gIn,
                                                 const float* __restrict__ beIn,
                                                 const ushort_t* __restrict__ Wb,
                                                 const float* __restrict__ bias,
                                                 ushort_t* __restrict__ Y,
                                                 float* __restrict__ statsOut) {
    __shared__ __align__(16) short xa[64][136];    // 64 rows x 128 k bf16
    __shared__ __align__(16) short wb[128][136];   // 128 co x 128 k bf16
    __shared__ float blk_s[CC], blk_q[CC];         // epilogue stat accumulators
    __shared__ float sc_l[CC], sh_l[CC];           // MODE 1 BN scale/shift

    const int row0 = blockIdx.x * 64;

    // ---- X tile staging (+ fused transform) ----
    if constexpr (MODE == 0) {
        const float* feat2 = (const float*)Xsrc_;
        __shared__ int   lidx[QB][3];
        __shared__ float lw[QB][3];
        {   // exact fp64 re-rank of this block's 64 queries; 4 thr/query
            double* rrd = (double*)&xa[0][0];   // [64][4][3] = 6144 B scratch
            int*    rri = (int*)&wb[0][0];      // [64][4][3] = 3072 B scratch
            const int ql = threadIdx.x >> 2;
            const int pp = threadIdx.x & 3;
            const int qg = row0 + ql;
            const double qx = (double)pos1[qg * 3 + 0];
            const double qy = (double)pos1[qg * 3 + 1];
            const double qz = (double)pos1[qg * 3 + 2];
            double b0 = DBL_BIG, b1 = DBL_BIG, b2 = DBL_BIG;
            int    j0 = IDX_BIG, j1 = IDX_BIG, j2 = IDX_BIG;
            const uint4* kp = (const uint4*)(skeys + (size_t)qg * NSURV + pp * 12);
#pragma unroll
            for (int gi = 0; gi < 3; ++gi) {
                const uint4 kk = kp[gi];
                const unsigned ks[4] = {kk.x, kk.y, kk.z, kk.w};
#pragma unroll
                for (int u = 0; u < 4; ++u) {
                    const int id = (int)(ks[u] & IMASK);
                    const float4 cf = pos2f4[id];   // one aligned 16B load
                    const double x = (double)cf.x;
                    const double y = (double)cf.y;
                    const double z = (double)cf.z;
                    const double ax = qx - x, ay = qy - y, az = qz - z;
                    const double d = ax * ax + ay * ay + az * az;
                    const bool l2 = (d < b2) || (d == b2 && id < j2);
                    if (l2) {
                        const bool l1 = (d < b1) || (d == b1 && id < j1);
                        const bool l0 = (d < b0) || (d == b0 && id < j0);
                        b2 = l1 ? b1 : d;              j2 = l1 ? j1 : id;
                        b1 = l1 ? (l0 ? b0 : d) : b1;  j1 = l1 ? (l0 ? j0 : id) : j1;
                        b0 = l0 ? d : b0;              j0 = l0 ? id : j0;
                    }
                }
            }
            const int base = (ql * 4 + pp) * 3;
            rrd[base + 0] = b0; rri[base + 0] = j0;
            rrd[base + 1] = b1; rri[base + 1] = j1;
            rrd[base + 2] = b2; rri[base + 2] = j2;
            __syncthreads();
            if (threadIdx.x < QB) {
                const int qq = threadIdx.x;
                double c0 = DBL_BIG, c1 = DBL_BIG, c2 = DBL_BIG;
                int    i0 = IDX_BIG, i1 = IDX_BIG, i2 = IDX_BIG;
#pragma unroll
                for (int s = 0; s < 12; ++s) {
                    const double d = rrd[qq * 12 + s];
                    const int   id = rri[qq * 12 + s];
                    const bool l2 = (d < c2) || (d == c2 && id < i2);
                    if (l2) {
                        const bool l1 = (d < c1) || (d == c1 && id < i1);
                        const bool l0 = (d < c0) || (d == c0 && id < i0);
                        c2 = l1 ? c1 : d;              i2 = l1 ? i1 : id;
                        c1 = l1 ? (l0 ? c0 : d) : c1;  i1 = l1 ? (l0 ? i0 : id) : i1;
                        c0 = l0 ? d : c0;              i0 = l0 ? id : i0;
                    }
                }
                const double r0 = 1.0 / (c0 + EPS_D);
                const double r1 = 1.0 / (c1 + EPS_D);
                const double r2 = 1.0 / (c2 + EPS_D);
                const double inv = 1.0 / (r0 + r1 + r2);
                lidx[qq][0] = i0; lidx[qq][1] = i1; lidx[qq][2] = i2;
                lw[qq][0] = (float)(r0 * inv);
                lw[qq][1] = (float)(r1 * inv);
                lw[qq][2] = (float)(r2 * inv);
            }
            __syncthreads();
        }
        if (threadIdx.x < CC) { blk_s[threadIdx.x] = 0.f; blk_q[threadIdx.x] = 0.f; }
#pragma unroll
        for (int e = threadIdx.x; e < 64 * 32; e += 256) {
            const int r = e >> 5, c4 = e & 31;
            const int i0 = lidx[r][0], i1 = lidx[r][1], i2 = lidx[r][2];
            const float w0 = lw[r][0], w1 = lw[r][1], w2 = lw[r][2];
            const float4 f0 = *(const float4*)&feat2[(size_t)i0 * CC + c4 * 4];
            const float4 f1 = *(const float4*)&feat2[(size_t)i1 * CC + c4 * 4];
            const float4 f2 = *(const float4*)&feat2[(size_t)i2 * CC + c4 * 4];
            float4 v;
            v.x = w0 * f0.x + w1 * f1.x + w2 * f2.x;
            v.y = w0 * f0.y + w1 * f1.y + w2 * f2.y;
            v.z = w0 * f0.z + w1 * f1.z + w2 * f2.z;
            v.w = w0 * f0.w + w1 * f1.w + w2 * f2.w;
            unsigned* dst = (unsigned*)&xa[r][0];
            dst[c4 * 2 + 0] = bf16pair(v.x, v.y);
            dst[c4 * 2 + 1] = bf16pair(v.z, v.w);
        }
    } else {
        const ushort_t* Xbf = (const ushort_t*)Xsrc_;
        // ---- BN prologue: reduce 8-group stats -> scale/shift in LDS ----
        if (threadIdx.x < CC) {
            const int c = threadIdx.x;
            float s = 0.f, q = 0.f;
#pragma unroll
            for (int gr = 0; gr < NGRP; ++gr) {
                s += statsIn[gr * 256 + c];
                q += statsIn[gr * 256 + CC + c];
            }
            const float m = s * (1.f / (float)NQ);
            const float v = fmaf(-m, m, q * (1.f / (float)NQ));
            const float rstd = rsqrtf(v + EPS_BN);
            const float scl = gIn[c] * rstd;
            sc_l[c] = scl;
            sh_l[c] = fmaf(-m, scl, beIn[c]);
            blk_s[c] = 0.f; blk_q[c] = 0.f;
        }
        __syncthreads();
        // X staging: uint4 = 8 bf16 per iter, 4 iters/thread
#pragma unroll
        for (int e = threadIdx.x; e < 64 * 16; e += 256) {
            const int r = e >> 4, c8 = e & 15;
            const uint4 u = *(const uint4*)&Xbf[(size_t)(row0 + r) * CC + c8 * 8];
            const float4 s0 = *(const float4*)&sc_l[c8 * 8];
            const float4 s1 = *(const float4*)&sc_l[c8 * 8 + 4];
            const float4 h0 = *(const float4*)&sh_l[c8 * 8];
            const float4 h1 = *(const float4*)&sh_l[c8 * 8 + 4];
            const float v0 = fmaxf(fmaf(bflo(u.x), s0.x, h0.x), 0.f);
            const float v1 = fmaxf(fmaf(bfhi(u.x), s0.y, h0.y), 0.f);
            const float v2 = fmaxf(fmaf(bflo(u.y), s0.z, h0.z), 0.f);
            const float v3 = fmaxf(fmaf(bfhi(u.y), s0.w, h0.w), 0.f);
            const float v4 = fmaxf(fmaf(bflo(u.z), s1.x, h1.x), 0.f);
            const float v5 = fmaxf(fmaf(bfhi(u.z), s1.y, h1.y), 0.f);
            const float v6 = fmaxf(fmaf(bflo(u.w), s1.z, h1.z), 0.f);
            const float v7 = fmaxf(fmaf(bfhi(u.w), s1.w, h1.w), 0.f);
            uint4 o;
            o.x = bf16pair(v0, v1); o.y = bf16pair(v2, v3);
            o.z = bf16pair(v4, v5); o.w = bf16pair(v6, v7);
            *(uint4*)&xa[r][c8 * 8] = o;
        }
    }
    // ---- W tile staging: pre-converted bf16, 16B copies ----
#pragma unroll
    for (int e = threadIdx.x; e < 128 * 16; e += 256) {
        const int co = e >> 4, seg = e & 15;
        *(float4*)&wb[co][seg * 8] = *(const float4*)&Wb[(size_t)co * CC + seg * 8];
    }
    __syncthreads();

    const int lane = threadIdx.x & 63;
    const int wv = threadIdx.x >> 6;     // wave -> rows 16*wv..+15
    const int nn = lane & 15;
    const int quad = lane >> 4;

    floatx4 acc[8] = {};

    const short* arow = &xa[wv * 16 + nn][0];
#pragma unroll
    for (int ks = 0; ks < 4; ++ks) {
        const bf16x8 a = *(const bf16x8*)(arow + ks * 32 + quad * 8);
#pragma unroll
        for (int ct = 0; ct < 8; ++ct) {
            const bf16x8 b = *(const bf16x8*)(&wb[ct * 16 + nn][0] + ks * 32 + quad * 8);
            acc[ct] = __builtin_amdgcn_mfma_f32_16x16x32_bf16(a, b, acc[ct], 0, 0, 0);
        }
    }

    // ---- epilogue: bias, bf16 Y store, column stats (fp32) ----
#pragma unroll
    for (int ct = 0; ct < 8; ++ct) {
        const float bv = bias[ct * 16 + nn];
        float s = 0.f, qv = 0.f;
#pragma unroll
        for (int r = 0; r < 4; ++r) {
            acc[ct][r] += bv;
            s += acc[ct][r];
            qv = fmaf(acc[ct][r], acc[ct][r], qv);
        }
#pragma unroll
        for (int r = 0; r < 4; ++r)
            Y[(size_t)(row0 + wv * 16 + quad * 4 + r) * CC + ct * 16 + nn] = bf16one(acc[ct][r]);
        s += __shfl_xor(s, 16, 64); s += __shfl_xor(s, 32, 64);
        qv += __shfl_xor(qv, 16, 64); qv += __shfl_xor(qv, 32, 64);
        if (quad == 0) {
            atomicAdd(&blk_s[ct * 16 + nn], s);
            atomicAdd(&blk_q[ct * 16 + nn], qv);
        }
    }
    __syncthreads();
    // 8-group global stats: low-contention atomicAdd (2048 addresses)
    {
        const int ch = threadIdx.x;
        const float v = (ch < CC) ? blk_s[ch] : blk_q[ch - CC];
        atomicAdd(&statsOut[(blockIdx.x & (NGRP - 1)) * 256 + ch], v);
    }
}

// ---------------------------------------------------------------------------
// Final BN + ReLU with in-kernel stats reduce; bf16 in, fp32 out.
// grid = 512 x 256; each thread handles 4 x 8 elements.
// ---------------------------------------------------------------------------
__global__ __launch_bounds__(256) void bn_final(const ushort_t* __restrict__ Y,
                                                const float* __restrict__ statsIn,
                                                const float* __restrict__ g,
                                                const float* __restrict__ be,
                                                float* __restrict__ out) {
    __shared__ float sc_l[CC], sh_l[CC];
    if (threadIdx.x < CC) {
        const int c = threadIdx.x;
        float s = 0.f, q = 0.f;
#pragma unroll
        for (int gr = 0; gr < NGRP; ++gr) {
            s += statsIn[gr * 256 + c];
            q += statsIn[gr * 256 + CC + c];
        }
        const float m = s * (1.f / (float)NQ);
        const float v = fmaf(-m, m, q * (1.f / (float)NQ));
        const float rstd = rsqrtf(v + EPS_BN);
        const float scl = g[c] * rstd;
        sc_l[c] = scl;
        sh_l[c] = fmaf(-m, scl, be[c]);
    }
    __syncthreads();
    const int base = blockIdx.x * 1024 + threadIdx.x;   // 8-col group index
#pragma unroll
    for (int it = 0; it < 4; ++it) {
        const int i8 = base + it * 256;
        const int c8 = (i8 & 15) * 8;
        const uint4 u = *(const uint4*)&Y[(size_t)i8 * 8];
        const float4 s0 = *(const float4*)&sc_l[c8];
        const float4 s1 = *(const float4*)&sc_l[c8 + 4];
        const float4 h0 = *(const float4*)&sh_l[c8];
        const float4 h1 = *(const float4*)&sh_l[c8 + 4];
        float4 o0, o1;
        o0.x = fmaxf(fmaf(bflo(u.x), s0.x, h0.x), 0.f);
        o0.y = fmaxf(fmaf(bfhi(u.x), s0.y, h0.y), 0.f);
        o0.z = fmaxf(fmaf(bflo(u.y), s0.z, h0.z), 0.f);
        o0.w = fmaxf(fmaf(bfhi(u.y), s0.w, h0.w), 0.f);
        o1.x = fmaxf(fmaf(bflo(u.z), s1.x, h1.x), 0.f);
        o1.y = fmaxf(fmaf(bfhi(u.z), s1.y, h1.y), 0.f);
        o1.z = fmaxf(fmaf(bflo(u.w), s1.z, h1.z), 0.f);
        o1.w = fmaxf(fmaf(bfhi(u.w), s1.w, h1.w), 0.f);
        ((float4*)out)[i8 * 2 + 0] = o0;
        ((float4*)out)[i8 * 2 + 1] = o1;
    }
}

// ---------------------------------------------------------------------------
extern "C" void kernel_launch(void* const* d_in, const int* in_sizes, int n_in,
                              void* d_out, int out_size, void* d_ws, size_t ws_size,
                              hipStream_t stream) {
    (void)in_sizes; (void)n_in; (void)out_size; (void)ws_size;

    const float* pos1  = (const float*)d_in[0];
    const float* pos2  = (const float*)d_in[1];
    const float* feat2 = (const float*)d_in[2];
    const float* Wl[3]  = {(const float*)d_in[3], (const float*)d_in[7],  (const float*)d_in[11]};
    const float* bl[3]  = {(const float*)d_in[4], (const float*)d_in[8],  (const float*)d_in[12]};
    const float* gl[3]  = {(const float*)d_in[5], (const float*)d_in[9],  (const float*)d_in[13]};
    const float* bel[3] = {(const float*)d_in[6], (const float*)d_in[10], (const float*)d_in[14]};

    // Workspace layout
    float* ws = (float*)d_ws;
    ushort_t* B0 = (ushort_t*)ws;                   // NQ*CC bf16 (8 MB)
    ushort_t* B1 = B0 + (size_t)NQ * CC;            // NQ*CC bf16 (8 MB)
    unsigned* skeys = (unsigned*)(B1 + (size_t)NQ * CC);   // NQ*48 u32 (6 MB)
    float* stats = (float*)(skeys + (size_t)NQ * NSURV);   // 3*NGRP*256 floats
    ushort_t* Wbf = (ushort_t*)(stats + 3 * NGRP * 256);   // 3*16384 bf16
    uint4* ptile = (uint4*)(Wbf + 3 * CC * CC);            // (256+2)*64 uint4 (264 KB)
    float4* pos2f4 = (float4*)(ptile + (size_t)258 * 64);  // MC*16 B (128 KB)

    float* st0 = stats + 0 * NGRP * 256;
    float* st1 = stats + 1 * NGRP * 256;
    float* st2 = stats + 2 * NGRP * 256;

    // 0: pack pos2 -> MFMA tiles + float4 copy (precedes knn/gemm0)
    pack_kernel<<<MC / TB, TB, 0, stream>>>(pos2, ptile, pos2f4);
    // 1: KNN scan (32x32 MFMA, 7-bit keys) + W bf16 prep + stats zero
    knn_kernel<<<KNN_B + 16, TB, 0, stream>>>(pos1, ptile, skeys,
                                              Wl[0], Wl[1], Wl[2], Wbf, stats);
    // 2: layer 0 (rerank + interp fused) -> B0 (bf16), st0
    gemm_mfma<0><<<GEMM_B, 256, 0, stream>>>(feat2, skeys, pos1, pos2f4,
                                             nullptr, nullptr, nullptr,
                                             Wbf + 0 * CC * CC, bl[0], B0, st0);
    // 3: layer 1 (stats-reduce + BN fused) -> B1 (bf16), st1
    gemm_mfma<1><<<GEMM_B, 256, 0, stream>>>(B0, nullptr, nullptr, nullptr,
                                             st0, gl[0], bel[0],
                                             Wbf + 1 * CC * CC, bl[1], B1, st1);
    // 4: layer 2 -> B0 (bf16), st2
    gemm_mfma<1><<<GEMM_B, 256, 0, stream>>>(B1, nullptr, nullptr, nullptr,
                                             st1, gl[1], bel[1],
                                             Wbf + 2 * CC * CC, bl[2], B0, st2);
    // 5: final BN+ReLU (stats-reduce fused) -> out (fp32)
    bn_final<<<GEMM_B, 256, 0, stream>>>(B0, st2, gl[2], bel[2], (float*)d_out);
}

// Round 9
// 189.389 us; speedup vs baseline: 1.1196x; 1.0069x over previous
//
#include <hip/hip_runtime.h>
#include <hip/hip_fp16.h>
#include <math.h>

// Problem constants (from reference)
#define NQ 32768   // query points (pos1)
#define MC 8192    // source points (pos2)
#define CC 128     // channels
#define EPS_BN 1e-5f
#define EPS_D  1e-8

#define DBL_BIG 1e300
#define IDX_BIG 0x7fffffff

// KNN config (R15: R13 verified structure + forced v_and_or_b32 key pack
// (mask in SGPR via asm "s" constraint -- VOP3 can't take the literal))
#define QB  64          // queries per block (2 tiles of 32)
#define TB  256         // threads per block (4 waves)
#define PCE 2048        // piece of M per block
#define NT  32          // 32-cand tiles per wave (1024 cands)
#define KM7 0xFFFFFF80u     // scan keys: keep sign+exp+16 mant, low 7 = (t<<2)|r
#define KMASK 0xFFFFE000u   // dump keys: sign+exp+10 mant, low 13 = cand index
#define IMASK 0x1FFFu       // 13-bit index (M=8192)
#define NSURV 48            // survivors/query (4 pieces x 2 wh x 2 h x 3)
#define KNN_B ((NQ / QB) * 4)   // 2048 scan blocks
#define GEMM_B (NQ / 64)        // 512
#define NGRP 8                  // stats atomic groups (2048 addresses)

typedef __attribute__((ext_vector_type(8))) short bf16x8;     // 8 bf16
typedef __attribute__((ext_vector_type(8))) _Float16 half8;   // 8 f16
typedef __attribute__((ext_vector_type(4))) float floatx4;    // 16x16 acc
typedef __attribute__((ext_vector_type(16))) float floatx16;  // 32x32 acc
typedef unsigned short ushort_t;

// RNE fp32 -> bf16 pair packed in u32 (lo = a, hi = b)
__device__ __forceinline__ unsigned bf16pair(float a, float b) {
    unsigned ua = __float_as_uint(a); ua = (ua + 0x7FFFu + ((ua >> 16) & 1u)) >> 16;
    unsigned ub = __float_as_uint(b); ub = (ub + 0x7FFFu + ((ub >> 16) & 1u)) >> 16;
    return ua | (ub << 16);
}
__device__ __forceinline__ ushort_t bf16one(float a) {
    unsigned ua = __float_as_uint(a);
    return (ushort_t)((ua + 0x7FFFu + ((ua >> 16) & 1u)) >> 16);
}
// unpack u32 = (lo bf16, hi bf16) -> 2 fp32
__device__ __forceinline__ float bflo(unsigned u) { return __uint_as_float(u << 16); }
__device__ __forceinline__ float bfhi(unsigned u) { return __uint_as_float(u & 0xFFFF0000u); }

// Branchless insert of x into ascending top-3 (k0<=k1<=k2):
// 1x v_min_f32 + 2x v_med3_f32.
__device__ __forceinline__ void ins3(float& k0, float& k1, float& k2, float x) {
    const float n0 = fminf(k0, x);
    const float n1 = __builtin_amdgcn_fmed3f(k0, k1, x);
    const float n2 = __builtin_amdgcn_fmed3f(k1, k2, x);
    k0 = n0; k1 = n1; k2 = n2;
}

// Single-instruction (d & m) | ir with the mask held in an SGPR.
// (C-level form emits and+or: VOP3 v_and_or_b32 cannot encode the literal.)
__device__ __forceinline__ unsigned vandor(unsigned d, unsigned m, unsigned ir) {
    unsigned r;
    asm("v_and_or_b32 %0, %1, %2, %3" : "=v"(r) : "v"(d), "s"(m), "v"(ir));
    return r;
}

#define PK2(a, b) ((unsigned)__half_as_ushort(a) | ((unsigned)__half_as_ushort(b) << 16))

// ---------------------------------------------------------------------------
// Pack pos2 -> (a) 32x32x16 MFMA A-fragment tiles of split-f16 ext vectors,
//              (b) pos2f4: float4 {x,y,z,0} for the gemm rerank.
// A slots (16): [ch3, cl3, ch3, cl3, hchi, hclo, 1, 1]; pairs with
// B = [-ph3, -ph3, -pl3, -pl3, 1, 1, hphi, hplo] -> sum = 0.5d^2.
// Tile t (32 cands): lane l reads uint4 at t*64 + (l>>5)*32 + (l&31).
// ---------------------------------------------------------------------------
__global__ __launch_bounds__(TB) void pack_kernel(const float* __restrict__ pos2,
                                                  uint4* __restrict__ ptile,
                                                  float4* __restrict__ pos2f4) {
    const int c = blockIdx.x * TB + threadIdx.x;   // grid 32 x 256 = 8192
    const float x = pos2[c * 3 + 0];
    const float y = pos2[c * 3 + 1];
    const float z = pos2[c * 3 + 2];
    float4 p4; p4.x = x; p4.y = y; p4.z = z; p4.w = 0.f;
    pos2f4[c] = p4;
    const __half chx = __float2half(x); const float fchx = __half2float(chx);
    const __half chy = __float2half(y); const float fchy = __half2float(chy);
    const __half chz = __float2half(z); const float fchz = __half2float(chz);
    const __half clx = __float2half(x - fchx);
    const __half cly = __float2half(y - fchy);
    const __half clz = __float2half(z - fchz);
    const double X = (double)fchx + (double)__half2float(clx);
    const double Y = (double)fchy + (double)__half2float(cly);
    const double Z = (double)fchz + (double)__half2float(clz);
    const double hc = 0.5 * (X * X + Y * Y + Z * Z);
    const __half hchi = __float2half((float)hc);
    const __half hclo = __float2half((float)(hc - (double)__half2float(hchi)));
    const __half one = __float2half(1.0f);
    uint4 a0, a1;
    a0.x = PK2(chx, chy); a0.y = PK2(chz, clx); a0.z = PK2(cly, clz); a0.w = PK2(chx, chy);
    a1.x = PK2(chz, clx); a1.y = PK2(cly, clz); a1.z = PK2(hchi, hclo); a1.w = PK2(one, one);
    const int t = c >> 5, m = c & 31;
    ptile[(size_t)t * 64 + m]      = a0;   // k 0..7
    ptile[(size_t)t * 64 + 32 + m] = a1;   // k 8..15
    if (blockIdx.x == 0 && threadIdx.x < 128) {   // 2 zero pad tiles
        uint4 zf = {0u, 0u, 0u, 0u};
        ptile[(size_t)256 * 64 + threadIdx.x] = zf;
    }
}

// ---------------------------------------------------------------------------
// KNN scan (32x32 MFMA) + piggy-backed weight conversion + stats zero.
// Blocks [0, KNN_B): 64 queries x one quarter of M. Waves {0,1} own query
//   tile 0 (cols 0..31), {2,3} tile 1; wave half wh scans 1024 cands = 32
//   tiles. Per tile: 1 load (16B/lane), 1 MFMA (intrinsic; compiler inserts
//   the MFMA->VALU hazard nops), 16 keys (single v_and_or each via asm,
//   7-bit idx (t<<2)|r shared across the 4 chains) into 4 independent top-3
//   chains. End of wave: decode 12 survivors to 13-bit keys, merge, dump 3.
// Blocks [KNN_B, KNN_B+16): W fp32 -> bf16 conversion; first zeroes stats.
// ---------------------------------------------------------------------------
__global__ __launch_bounds__(TB) void knn_kernel(const float* __restrict__ pos1,
                                                 const uint4* __restrict__ ptile,
                                                 unsigned* __restrict__ skeys,
                                                 const float* __restrict__ W0,
                                                 const float* __restrict__ W1,
                                                 const float* __restrict__ W2,
                                                 ushort_t* __restrict__ Wbf,
                                                 float* __restrict__ stats) {
    __shared__ __align__(16) ushort_t qext[QB][16];   // 2 KB query ext vectors

    if (blockIdx.x >= KNN_B) {                 // ---- prep blocks ----
        const int pb = blockIdx.x - KNN_B;     // 0..15
        const int f = pb * TB + threadIdx.x;   // float4 index within a layer
        const float* Ws[3] = {W0, W1, W2};
#pragma unroll
        for (int l = 0; l < 3; ++l) {
            const float4 v = ((const float4*)Ws[l])[f];
            unsigned* dst = (unsigned*)(Wbf + (size_t)l * CC * CC);
            dst[f * 2 + 0] = bf16pair(v.x, v.y);
            dst[f * 2 + 1] = bf16pair(v.z, v.w);
        }
        if (pb == 0)
            for (int i = threadIdx.x; i < 3 * NGRP * 256; i += TB) stats[i] = 0.f;
        return;
    }

    const int piece = blockIdx.x & 3;
    const int bq    = blockIdx.x >> 2;

    // ---- query ext staging: thread i builds query (bq*64+i)'s B vector ----
    // B (16 slots): [-ph x3, -ph x3, -pl x3, -pl x3, 1, 1, hphi, hplo]
    if (threadIdx.x < QB) {
        const int qq = bq * QB + threadIdx.x;
        const float x = pos1[qq * 3 + 0];
        const float y = pos1[qq * 3 + 1];
        const float z = pos1[qq * 3 + 2];
        const __half phx = __float2half(x); const float fphx = __half2float(phx);
        const __half phy = __float2half(y); const float fphy = __half2float(phy);
        const __half phz = __float2half(z); const float fphz = __half2float(phz);
        const __half plx = __float2half(x - fphx);
        const __half ply = __float2half(y - fphy);
        const __half plz = __float2half(z - fphz);
        const double X = (double)fphx + (double)__half2float(plx);
        const double Y = (double)fphy + (double)__half2float(ply);
        const double Z = (double)fphz + (double)__half2float(plz);
        const double hp = 0.5 * (X * X + Y * Y + Z * Z);
        const __half hphi = __float2half((float)hp);
        const __half hplo = __float2half((float)(hp - (double)__half2float(hphi)));
        const ushort_t SG = 0x8000u;   // f16 sign flip = exact negation
        const ushort_t nx = (ushort_t)(__half_as_ushort(phx) ^ SG);
        const ushort_t ny = (ushort_t)(__half_as_ushort(phy) ^ SG);
        const ushort_t nz = (ushort_t)(__half_as_ushort(phz) ^ SG);
        const ushort_t mx = (ushort_t)(__half_as_ushort(plx) ^ SG);
        const ushort_t my = (ushort_t)(__half_as_ushort(ply) ^ SG);
        const ushort_t mz = (ushort_t)(__half_as_ushort(plz) ^ SG);
        const ushort_t on = __half_as_ushort(__float2half(1.0f));
        ushort_t* e = &qext[threadIdx.x][0];
        e[0] = nx; e[1] = ny; e[2] = nz; e[3] = nx; e[4]  = ny; e[5]  = nz;
        e[6] = mx; e[7] = my; e[8] = mz; e[9] = mx; e[10] = my; e[11] = mz;
        e[12] = on; e[13] = on;
        e[14] = __half_as_ushort(hphi); e[15] = __half_as_ushort(hplo);
    }
    __syncthreads();

    const int lane = threadIdx.x & 63;
    const int w    = threadIdx.x >> 6;
    const int qt   = w >> 1;            // query tile (0/1)
    const int wh   = w & 1;             // candidate half within piece
    const int col  = lane & 31;         // query column / candidate row
    const int h    = lane >> 5;         // k-slice (0/1)

    // B fragment: query col's ext vector, k-slice h*8..+8
    const uint4 bqu = *(const uint4*)&qext[qt * 32 + col][h * 8];
    const half8 bqh = *(const half8*)&bqu;

    // A stream: lane's fixed slot within each 1KB tile
    const int cw = piece * PCE + wh * 1024;   // wave's candidate base
    const uint4* lp = ptile + (size_t)(cw >> 5) * 64 + h * 32 + col;
#define LD(t) lp[(size_t)(t) * 64]

    const float KINIT = __uint_as_float(0x7F000000u);   // large finite sentinel
    float a0 = KINIT, a1 = KINIT, a2 = KINIT;   // 4 independent top-3 chains
    float b0 = KINIT, b1 = KINIT, b2 = KINIT;   // (chain q covers rows 8q+..)
    float c0 = KINIT, c1 = KINIT, c2 = KINIT;
    float e0 = KINIT, e1 = KINIT, e2 = KINIT;
    // shared per-tile index regs: (t<<2)|r, r = reg&3 (same for all chains)
    unsigned i0 = 0u, i1 = 1u, i2 = 2u, i3 = 3u;
    const unsigned km7 = KM7;   // pinned to SGPR by the asm "s" constraint
    const floatx16 zc = {0.f,0.f,0.f,0.f,0.f,0.f,0.f,0.f,0.f,0.f,0.f,0.f,0.f,0.f,0.f,0.f};

#define KEY1(v, ir, K0, K1, K2) { \
        const unsigned u_ = vandor(__float_as_uint(v), km7, ir); \
        ins3(K0, K1, K2, __uint_as_float(u_)); }
#define KEYS(d) { \
        KEY1(d[0],  i0, a0, a1, a2); KEY1(d[1],  i1, a0, a1, a2); \
        KEY1(d[2],  i2, a0, a1, a2); KEY1(d[3],  i3, a0, a1, a2); \
        KEY1(d[4],  i0, b0, b1, b2); KEY1(d[5],  i1, b0, b1, b2); \
        KEY1(d[6],  i2, b0, b1, b2); KEY1(d[7],  i3, b0, b1, b2); \
        KEY1(d[8],  i0, c0, c1, c2); KEY1(d[9],  i1, c0, c1, c2); \
        KEY1(d[10], i2, c0, c1, c2); KEY1(d[11], i3, c0, c1, c2); \
        KEY1(d[12], i0, e0, e1, e2); KEY1(d[13], i1, e0, e1, e2); \
        KEY1(d[14], i2, e0, e1, e2); KEY1(d[15], i3, e0, e1, e2); \
        i0 += 4u; i1 += 4u; i2 += 4u; i3 += 4u; }

    uint4 LA = LD(0);
    uint4 LB = LD(1);
    for (int t = 0; t < NT; t += 2) {
        const floatx16 dv = __builtin_amdgcn_mfma_f32_32x32x16_f16(*(const half8*)&LA, bqh, zc, 0, 0, 0);
        LA = LD(t + 2);   // overshoots into pad tiles on last iter (never consumed)
        KEYS(dv);
        const floatx16 dw = __builtin_amdgcn_mfma_f32_32x32x16_f16(*(const half8*)&LB, bqh, zc, 0, 0, 0);
        LB = LD(t + 3);
        KEYS(dw);
    }
#undef LD
#undef KEYS
#undef KEY1

    // decode chain survivors (7-bit idx -> global cand index, 13-bit key)
    // row = r + 8*chain + 4*h; j = cw + t*32 + row
#define REKEY(kf, q) __uint_as_float((__float_as_uint(kf) & KMASK) | \
        (unsigned)(cw + (int)((__float_as_uint(kf) & 0x7Fu) >> 2) * 32 + \
                   (int)(__float_as_uint(kf) & 3u) + 8 * (q) + 4 * h))
    float m0 = KINIT, m1 = KINIT, m2 = KINIT;
    ins3(m0, m1, m2, REKEY(a0, 0)); ins3(m0, m1, m2, REKEY(a1, 0)); ins3(m0, m1, m2, REKEY(a2, 0));
    ins3(m0, m1, m2, REKEY(b0, 1)); ins3(m0, m1, m2, REKEY(b1, 1)); ins3(m0, m1, m2, REKEY(b2, 1));
    ins3(m0, m1, m2, REKEY(c0, 2)); ins3(m0, m1, m2, REKEY(c1, 2)); ins3(m0, m1, m2, REKEY(c2, 2));
    ins3(m0, m1, m2, REKEY(e0, 3)); ins3(m0, m1, m2, REKEY(e1, 3)); ins3(m0, m1, m2, REKEY(e2, 3));
#undef REKEY

    // dump: query q's survivors at skeys[q*48 + piece*12 + wh*6 + h*3 + slot]
    {
        const int q = bq * QB + qt * 32 + col;
        unsigned* dst = skeys + (size_t)q * NSURV + piece * 12 + wh * 6 + h * 3;
        dst[0] = __float_as_uint(m0);
        dst[1] = __float_as_uint(m1);
        dst[2] = __float_as_uint(m2);
    }
}

// ---------------------------------------------------------------------------
// bf16-MFMA fused layer GEMM: Y = Xin @ W^T + bias (fp32 accumulate).
//   MODE 0: prologue re-ranks this block's own 64 queries (fp64 exact) from
//           skeys (pos2 via packed float4), then Xin = interp(feat2, idx, w).
//   MODE 1: prologue reduces statsIn[8][256] -> BN scale/shift in LDS, then
//           Xin = relu(Xbf16 * sc[c] + sh[c]). Y out: bf16.
// grid = 512, block = 256.
// ---------------------------------------------------------------------------
template <int MODE>
__global__ __launch_bounds__(256) void gemm_mfma(const void* __restrict__ Xsrc_,
                                                 const unsigned* __restrict__ skeys,
                                                 const float* __restrict__ pos1,
                                                 const float4* __restrict__ pos2f4,
                                                 const float* __restrict__ statsIn,
                                                 const float* __restrict__ gIn,
                                                 const float* __restrict__ beIn,
                                                 const ushort_t* __restrict__ Wb,
                                                 const float* __restrict__ bias,
                                                 ushort_t* __restrict__ Y,
                                                 float* __restrict__ statsOut) {
    __shared__ __align__(16) short xa[64][136];    // 64 rows x 128 k bf16
    __shared__ __align__(16) short wb[128][136];   // 128 co x 128 k bf16
    __shared__ float blk_s[CC], blk_q[CC];         // epilogue stat accumulators
    __shared__ float sc_l[CC], sh_l[CC];           // MODE 1 BN scale/shift

    const int row0 = blockIdx.x * 64;

    // ---- X tile staging (+ fused transform) ----
    if constexpr (MODE == 0) {
        const float* feat2 = (const float*)Xsrc_;
        __shared__ int   lidx[QB][3];
        __shared__ float lw[QB][3];
        {   // exact fp64 re-rank of this block's 64 queries; 4 thr/query
            double* rrd = (double*)&xa[0][0];   // [64][4][3] = 6144 B scratch
            int*    rri = (int*)&wb[0][0];      // [64][4][3] = 3072 B scratch
            const int ql = threadIdx.x >> 2;
            const int pp = threadIdx.x & 3;
            const int qg = row0 + ql;
            const double qx = (double)pos1[qg * 3 + 0];
            const double qy = (double)pos1[qg * 3 + 1];
            const double qz = (double)pos1[qg * 3 + 2];
            double b0 = DBL_BIG, b1 = DBL_BIG, b2 = DBL_BIG;
            int    j0 = IDX_BIG, j1 = IDX_BIG, j2 = IDX_BIG;
            const uint4* kp = (const uint4*)(skeys + (size_t)qg * NSURV + pp * 12);
#pragma unroll
            for (int gi = 0; gi < 3; ++gi) {
                const uint4 kk = kp[gi];
                const unsigned ks[4] = {kk.x, kk.y, kk.z, kk.w};
#pragma unroll
                for (int u = 0; u < 4; ++u) {
                    const int id = (int)(ks[u] & IMASK);
                    const float4 cf = pos2f4[id];   // one aligned 16B load
                    const double x = (double)cf.x;
                    const double y = (double)cf.y;
                    const double z = (double)cf.z;
                    const double ax = qx - x, ay = qy - y, az = qz - z;
                    const double d = ax * ax + ay * ay + az * az;
                    const bool l2 = (d < b2) || (d == b2 && id < j2);
                    if (l2) {
                        const bool l1 = (d < b1) || (d == b1 && id < j1);
                        const bool l0 = (d < b0) || (d == b0 && id < j0);
                        b2 = l1 ? b1 : d;              j2 = l1 ? j1 : id;
                        b1 = l1 ? (l0 ? b0 : d) : b1;  j1 = l1 ? (l0 ? j0 : id) : j1;
                        b0 = l0 ? d : b0;              j0 = l0 ? id : j0;
                    }
                }
            }
            const int base = (ql * 4 + pp) * 3;
            rrd[base + 0] = b0; rri[base + 0] = j0;
            rrd[base + 1] = b1; rri[base + 1] = j1;
            rrd[base + 2] = b2; rri[base + 2] = j2;
            __syncthreads();
            if (threadIdx.x < QB) {
                const int qq = threadIdx.x;
                double c0 = DBL_BIG, c1 = DBL_BIG, c2 = DBL_BIG;
                int    i0 = IDX_BIG, i1 = IDX_BIG, i2 = IDX_BIG;
#pragma unroll
                for (int s = 0; s < 12; ++s) {
                    const double d = rrd[qq * 12 + s];
                    const int   id = rri[qq * 12 + s];
                    const bool l2 = (d < c2) || (d == c2 && id < i2);
                    if (l2) {
                        const bool l1 = (d < c1) || (d == c1 && id < i1);
                        const bool l0 = (d < c0) || (d == c0 && id < i0);
                        c2 = l1 ? c1 : d;              i2 = l1 ? i1 : id;
                        c1 = l1 ? (l0 ? c0 : d) : c1;  i1 = l1 ? (l0 ? i0 : id) : i1;
                        c0 = l0 ? d : c0;              i0 = l0 ? id : i0;
                    }
                }
                const double r0 = 1.0 / (c0 + EPS_D);
                const double r1 = 1.0 / (c1 + EPS_D);
                const double r2 = 1.0 / (c2 + EPS_D);
                const double inv = 1.0 / (r0 + r1 + r2);
                lidx[qq][0] = i0; lidx[qq][1] = i1; lidx[qq][2] = i2;
                lw[qq][0] = (float)(r0 * inv);
                lw[qq][1] = (float)(r1 * inv);
                lw[qq][2] = (float)(r2 * inv);
            }
            __syncthreads();
        }
        if (threadIdx.x < CC) { blk_s[threadIdx.x] = 0.f; blk_q[threadIdx.x] = 0.f; }
#pragma unroll
        for (int e = threadIdx.x; e < 64 * 32; e += 256) {
            const int r = e >> 5, c4 = e & 31;
            const int i0 = lidx[r][0], i1 = lidx[r][1], i2 = lidx[r][2];
            const float w0 = lw[r][0], w1 = lw[r][1], w2 = lw[r][2];
            const float4 f0 = *(const float4*)&feat2[(size_t)i0 * CC + c4 * 4];
            const float4 f1 = *(const float4*)&feat2[(size_t)i1 * CC + c4 * 4];
            const float4 f2 = *(const float4*)&feat2[(size_t)i2 * CC + c4 * 4];
            float4 v;
            v.x = w0 * f0.x + w1 * f1.x + w2 * f2.x;
            v.y = w0 * f0.y + w1 * f1.y + w2 * f2.y;
            v.z = w0 * f0.z + w1 * f1.z + w2 * f2.z;
            v.w = w0 * f0.w + w1 * f1.w + w2 * f2.w;
            unsigned* dst = (unsigned*)&xa[r][0];
            dst[c4 * 2 + 0] = bf16pair(v.x, v.y);
            dst[c4 * 2 + 1] = bf16pair(v.z, v.w);
        }
    } else {
        const ushort_t* Xbf = (const ushort_t*)Xsrc_;
        // ---- BN prologue: reduce 8-group stats -> scale/shift in LDS ----
        if (threadIdx.x < CC) {
            const int c = threadIdx.x;
            float s = 0.f, q = 0.f;
#pragma unroll
            for (int gr = 0; gr < NGRP; ++gr) {
                s += statsIn[gr * 256 + c];
                q += statsIn[gr * 256 + CC + c];
            }
            const float m = s * (1.f / (float)NQ);
            const float v = fmaf(-m, m, q * (1.f / (float)NQ));
            const float rstd = rsqrtf(v + EPS_BN);
            const float scl = gIn[c] * rstd;
            sc_l[c] = scl;
            sh_l[c] = fmaf(-m, scl, beIn[c]);
            blk_s[c] = 0.f; blk_q[c] = 0.f;
        }
        __syncthreads();
        // X staging: uint4 = 8 bf16 per iter, 4 iters/thread
#pragma unroll
        for (int e = threadIdx.x; e < 64 * 16; e += 256) {
            const int r = e >> 4, c8 = e & 15;
            const uint4 u = *(const uint4*)&Xbf[(size_t)(row0 + r) * CC + c8 * 8];
            const float4 s0 = *(const float4*)&sc_l[c8 * 8];
            const float4 s1 = *(const float4*)&sc_l[c8 * 8 + 4];
            const float4 h0 = *(const float4*)&sh_l[c8 * 8];
            const float4 h1 = *(const float4*)&sh_l[c8 * 8 + 4];
            const float v0 = fmaxf(fmaf(bflo(u.x), s0.x, h0.x), 0.f);
            const float v1 = fmaxf(fmaf(bfhi(u.x), s0.y, h0.y), 0.f);
            const float v2 = fmaxf(fmaf(bflo(u.y), s0.z, h0.z), 0.f);
            const float v3 = fmaxf(fmaf(bfhi(u.y), s0.w, h0.w), 0.f);
            const float v4 = fmaxf(fmaf(bflo(u.z), s1.x, h1.x), 0.f);
            const float v5 = fmaxf(fmaf(bfhi(u.z), s1.y, h1.y), 0.f);
            const float v6 = fmaxf(fmaf(bflo(u.w), s1.z, h1.z), 0.f);
            const float v7 = fmaxf(fmaf(bfhi(u.w), s1.w, h1.w), 0.f);
            uint4 o;
            o.x = bf16pair(v0, v1); o.y = bf16pair(v2, v3);
            o.z = bf16pair(v4, v5); o.w = bf16pair(v6, v7);
            *(uint4*)&xa[r][c8 * 8] = o;
        }
    }
    // ---- W tile staging: pre-converted bf16, 16B copies ----
#pragma unroll
    for (int e = threadIdx.x; e < 128 * 16; e += 256) {
        const int co = e >> 4, seg = e & 15;
        *(float4*)&wb[co][seg * 8] = *(const float4*)&Wb[(size_t)co * CC + seg * 8];
    }
    __syncthreads();

    const int lane = threadIdx.x & 63;
    const int wv = threadIdx.x >> 6;     // wave -> rows 16*wv..+15
    const int nn = lane & 15;
    const int quad = lane >> 4;

    floatx4 acc[8] = {};

    const short* arow = &xa[wv * 16 + nn][0];
#pragma unroll
    for (int ks = 0; ks < 4; ++ks) {
        const bf16x8 a = *(const bf16x8*)(arow + ks * 32 + quad * 8);
#pragma unroll
        for (int ct = 0; ct < 8; ++ct) {
            const bf16x8 b = *(const bf16x8*)(&wb[ct * 16 + nn][0] + ks * 32 + quad * 8);
            acc[ct] = __builtin_amdgcn_mfma_f32_16x16x32_bf16(a, b, acc[ct], 0, 0, 0);
        }
    }

    // ---- epilogue: bias, bf16 Y store, column stats (fp32) ----
#pragma unroll
    for (int ct = 0; ct < 8; ++ct) {
        const float bv = bias[ct * 16 + nn];
        float s = 0.f, qv = 0.f;
#pragma unroll
        for (int r = 0; r < 4; ++r) {
            acc[ct][r] += bv;
            s += acc[ct][r];
            qv = fmaf(acc[ct][r], acc[ct][r], qv);
        }
#pragma unroll
        for (int r = 0; r < 4; ++r)
            Y[(size_t)(row0 + wv * 16 + quad * 4 + r) * CC + ct * 16 + nn] = bf16one(acc[ct][r]);
        s += __shfl_xor(s, 16, 64); s += __shfl_xor(s, 32, 64);
        qv += __shfl_xor(qv, 16, 64); qv += __shfl_xor(qv, 32, 64);
        if (quad == 0) {
            atomicAdd(&blk_s[ct * 16 + nn], s);
            atomicAdd(&blk_q[ct * 16 + nn], qv);
        }
    }
    __syncthreads();
    // 8-group global stats: low-contention atomicAdd (2048 addresses)
    {
        const int ch = threadIdx.x;
        const float v = (ch < CC) ? blk_s[ch] : blk_q[ch - CC];
        atomicAdd(&statsOut[(blockIdx.x & (NGRP - 1)) * 256 + ch], v);
    }
}

// ---------------------------------------------------------------------------
// Final BN + ReLU with in-kernel stats reduce; bf16 in, fp32 out.
// grid = 512 x 256; each thread handles 4 x 8 elements.
// ---------------------------------------------------------------------------
__global__ __launch_bounds__(256) void bn_final(const ushort_t* __restrict__ Y,
                                                const float* __restrict__ statsIn,
                                                const float* __restrict__ g,
                                                const float* __restrict__ be,
                                                float* __restrict__ out) {
    __shared__ float sc_l[CC], sh_l[CC];
    if (threadIdx.x < CC) {
        const int c = threadIdx.x;
        float s = 0.f, q = 0.f;
#pragma unroll
        for (int gr = 0; gr < NGRP; ++gr) {
            s += statsIn[gr * 256 + c];
            q += statsIn[gr * 256 + CC + c];
        }
        const float m = s * (1.f / (float)NQ);
        const float v = fmaf(-m, m, q * (1.f / (float)NQ));
        const float rstd = rsqrtf(v + EPS_BN);
        const float scl = g[c] * rstd;
        sc_l[c] = scl;
        sh_l[c] = fmaf(-m, scl, be[c]);
    }
    __syncthreads();
    const int base = blockIdx.x * 1024 + threadIdx.x;   // 8-col group index
#pragma unroll
    for (int it = 0; it < 4; ++it) {
        const int i8 = base + it * 256;
        const int c8 = (i8 & 15) * 8;
        const uint4 u = *(const uint4*)&Y[(size_t)i8 * 8];
        const float4 s0 = *(const float4*)&sc_l[c8];
        const float4 s1 = *(const float4*)&sc_l[c8 + 4];
        const float4 h0 = *(const float4*)&sh_l[c8];
        const float4 h1 = *(const float4*)&sh_l[c8 + 4];
        float4 o0, o1;
        o0.x = fmaxf(fmaf(bflo(u.x), s0.x, h0.x), 0.f);
        o0.y = fmaxf(fmaf(bfhi(u.x), s0.y, h0.y), 0.f);
        o0.z = fmaxf(fmaf(bflo(u.y), s0.z, h0.z), 0.f);
        o0.w = fmaxf(fmaf(bfhi(u.y), s0.w, h0.w), 0.f);
        o1.x = fmaxf(fmaf(bflo(u.z), s1.x, h1.x), 0.f);
        o1.y = fmaxf(fmaf(bfhi(u.z), s1.y, h1.y), 0.f);
        o1.z = fmaxf(fmaf(bflo(u.w), s1.z, h1.z), 0.f);
        o1.w = fmaxf(fmaf(bfhi(u.w), s1.w, h1.w), 0.f);
        ((float4*)out)[i8 * 2 + 0] = o0;
        ((float4*)out)[i8 * 2 + 1] = o1;
    }
}

// ---------------------------------------------------------------------------
extern "C" void kernel_launch(void* const* d_in, const int* in_sizes, int n_in,
                              void* d_out, int out_size, void* d_ws, size_t ws_size,
                              hipStream_t stream) {
    (void)in_sizes; (void)n_in; (void)out_size; (void)ws_size;

    const float* pos1  = (const float*)d_in[0];
    const float* pos2  = (const float*)d_in[1];
    const float* feat2 = (const float*)d_in[2];
    const float* Wl[3]  = {(const float*)d_in[3], (const float*)d_in[7],  (const float*)d_in[11]};
    const float* bl[3]  = {(const float*)d_in[4], (const float*)d_in[8],  (const float*)d_in[12]};
    const float* gl[3]  = {(const float*)d_in[5], (const float*)d_in[9],  (const float*)d_in[13]};
    const float* bel[3] = {(const float*)d_in[6], (const float*)d_in[10], (const float*)d_in[14]};

    // Workspace layout
    float* ws = (float*)d_ws;
    ushort_t* B0 = (ushort_t*)ws;                   // NQ*CC bf16 (8 MB)
    ushort_t* B1 = B0 + (size_t)NQ * CC;            // NQ*CC bf16 (8 MB)
    unsigned* skeys = (unsigned*)(B1 + (size_t)NQ * CC);   // NQ*48 u32 (6 MB)
    float* stats = (float*)(skeys + (size_t)NQ * NSURV);   // 3*NGRP*256 floats
    ushort_t* Wbf = (ushort_t*)(stats + 3 * NGRP * 256);   // 3*16384 bf16
    uint4* ptile = (uint4*)(Wbf + 3 * CC * CC);            // (256+2)*64 uint4 (264 KB)
    float4* pos2f4 = (float4*)(ptile + (size_t)258 * 64);  // MC*16 B (128 KB)

    float* st0 = stats + 0 * NGRP * 256;
    float* st1 = stats + 1 * NGRP * 256;
    float* st2 = stats + 2 * NGRP * 256;

    // 0: pack pos2 -> MFMA tiles + float4 copy (precedes knn/gemm0)
    pack_kernel<<<MC / TB, TB, 0, stream>>>(pos2, ptile, pos2f4);
    // 1: KNN scan (32x32 MFMA, fused and_or keys) + W bf16 prep + stats zero
    knn_kernel<<<KNN_B + 16, TB, 0, stream>>>(pos1, ptile, skeys,
                                              Wl[0], Wl[1], Wl[2], Wbf, stats);
    // 2: layer 0 (rerank + interp fused) -> B0 (bf16), st0
    gemm_mfma<0><<<GEMM_B, 256, 0, stream>>>(feat2, skeys, pos1, pos2f4,
                                             nullptr, nullptr, nullptr,
                                             Wbf + 0 * CC * CC, bl[0], B0, st0);
    // 3: layer 1 (stats-reduce + BN fused) -> B1 (bf16), st1
    gemm_mfma<1><<<GEMM_B, 256, 0, stream>>>(B0, nullptr, nullptr, nullptr,
                                             st0, gl[0], bel[0],
                                             Wbf + 1 * CC * CC, bl[1], B1, st1);
    // 4: layer 2 -> B0 (bf16), st2
    gemm_mfma<1><<<GEMM_B, 256, 0, stream>>>(B1, nullptr, nullptr, nullptr,
                                             st1, gl[1], bel[1],
                                             Wbf + 2 * CC * CC, bl[2], B0, st2);
    // 5: final BN+ReLU (stats-reduce fused) -> out (fp32)
    bn_final<<<GEMM_B, 256, 0, stream>>>(B0, st2, gl[2], bel[2], (float*)d_out);
}